// Round 2
// baseline (1952.549 us; speedup 1.0000x reference)
//
#include <hip/hip_runtime.h>
#include <hip/hip_bf16.h>
#include <stdint.h>

#define HH 128

typedef __attribute__((ext_vector_type(8))) short short8;
typedef __attribute__((ext_vector_type(4))) float floatx4;

typedef __attribute__((address_space(3))) uint32_t lds_u32_t;
typedef const __attribute__((address_space(1))) uint32_t gbl_u32_t;

__device__ __forceinline__ void gl_lds16(const void* g, void* l) {
  __builtin_amdgcn_global_load_lds((gbl_u32_t*)g, (lds_u32_t*)l, 16, 0, 0);
}

__device__ __forceinline__ float bf2f(short v) {
  union { uint32_t u; float f; } x; x.u = ((uint32_t)(uint16_t)v) << 16; return x.f;
}
__device__ __forceinline__ short f2bf(float f) {
  union { float f; uint32_t u; } x; x.f = f;
  uint32_t r = x.u + 0x7fffu + ((x.u >> 16) & 1u);
  return (short)(r >> 16);
}

// read element i of a float tensor that is either fp32 (fl=0) or bf16 (fl=1)
__device__ __forceinline__ float rdf(const void* p, int i, int fl) {
  return fl ? bf2f(((const short*)p)[i]) : ((const float*)p)[i];
}

// ---------------- probes ----------------

// int64-vs-int32 layout of edge_index
__global__ void detect_idx(const int* __restrict__ eidx, int* flag) {
  __shared__ int nz;
  if (threadIdx.x == 0) nz = 0;
  __syncthreads();
  int any = 0;
  for (int i = threadIdx.x; i < 1024; i += 256) any |= (eidx[2 * i + 1] != 0);
  if (any) atomicOr(&nz, 1);
  __syncthreads();
  if (threadIdx.x == 0) *flag = (nz == 0) ? 1 : 0;  // 1 => int64 layout
}

// fp32-vs-bf16 of float tensors: bits 14:7 of each word are an exponent for
// packed bf16 (always in ~[110,135] for N(0,1) data) but uniform mantissa
// bits for fp32.
__global__ void detect_dtype(const uint32_t* __restrict__ p, int* dflag) {
  __shared__ int cnt;
  if (threadIdx.x == 0) cnt = 0;
  __syncthreads();
  uint32_t u = p[threadIdx.x];
  int e = (u >> 7) & 0xFF;
  if (e >= 100 && e <= 140) atomicAdd(&cnt, 1);
  __syncthreads();
  if (threadIdx.x == 0) *dflag = (cnt >= 192) ? 1 : 0;  // 1 => bf16
}

// ---------------- prep kernels ----------------

// build (N,64) bf16 padded input: col j<60: frame=j/6, c=j%6: c<3 loc else vel
__global__ void pad_input(const void* __restrict__ loc, const void* __restrict__ vel,
                          short* __restrict__ dst, const int* __restrict__ dflag) {
  int fl = *dflag;
  int idx = blockIdx.x * 256 + threadIdx.x;
  int j = idx & 63, i = idx >> 6;
  short v = 0;
  if (j < 60) {
    int f = j / 6, c = j % 6;
    float x = (c < 3) ? rdf(loc, (i * 10 + f) * 3 + c, fl)
                      : rdf(vel, (i * 10 + f) * 3 + (c - 3), fl);
    v = f2bf(x);
  }
  dst[idx] = v;
}

// src (L,K,N) row-major -> dst (L,Np,Kp) row-major bf16 (transpose + zero-pad)
__global__ void transpose_w(const void* __restrict__ src, short* __restrict__ dst,
                            int L, int K, int N, int Kp, int Np,
                            const int* __restrict__ dflag) {
  int fl = *dflag;
  int idx = blockIdx.x * 256 + threadIdx.x;
  int tot = L * Np * Kp;
  if (idx >= tot) return;
  int k = idx % Kp; int rest = idx / Kp; int n = rest % Np; int l = rest / Np;
  short v = 0;
  if (k < K && n < N) v = f2bf(rdf(src, (l * K + k) * N + n, fl));
  dst[idx] = v;
}

// convert n elements (either dtype) to fp32, zero-pad to npad
__global__ void cvt_f32(const void* __restrict__ src, float* __restrict__ dst,
                        int n, int npad, const int* __restrict__ dflag) {
  int fl = *dflag;
  int i = blockIdx.x * 256 + threadIdx.x;
  if (i < npad) dst[i] = (i < n) ? rdf(src, i, fl) : 0.0f;
}

// ---------------- fused 2-layer MLP kernel ----------------
// MODE: 0=EMBED(K1=64) 1=MSG(K1=256, gather+atomic-scatter) 2=UPD(K1=256) 3=HEAD(K1=128,N2=32)

template <int MODE>
__global__ __launch_bounds__(256, 2)
void mlp2_kernel(const short* __restrict__ Asrc, const float* __restrict__ aggin,
                 const int* __restrict__ eidx, const int* __restrict__ idxflag,
                 const short* __restrict__ W1T, const float* __restrict__ b1,
                 const short* __restrict__ W2T, const float* __restrict__ b2,
                 short* __restrict__ outbf, float* __restrict__ aggout,
                 float* __restrict__ outf, int Etot) {
  constexpr int K1 = (MODE == 0) ? 64 : (MODE == 3) ? 128 : 256;
  constexpr int NS = K1 / 32;
  constexpr int N2T = (MODE == 3) ? 2 : 8;

  __shared__ __align__(16) char lds[65536];

  const int tid = threadIdx.x;
  const int w = tid >> 6;
  const int lane = tid & 63;
  const int quad = lane >> 4;
  const int l16 = lane & 15;
  const int R0 = blockIdx.x * 128;

  // --- stage W1T as swizzled B-fragments, slots [s][t] of 1KB, async ---
  // slot(s,t) lane l holds W1T[n=t*16+(l&15)][k=s*32+(l>>4)*8 .. +8]
#pragma unroll
  for (int c = 0; c < NS * 2; ++c) {
    int slot = w * (NS * 2) + c;
    int s = slot >> 3, t = slot & 7;
    int n = t * 16 + l16, k = s * 32 + quad * 8;
    gl_lds16(W1T + n * K1 + k, lds + slot * 1024 + lane * 16);
  }

  // --- prefetch A fragments (A[m=l16][k=quad*8+j]) ---
  short8 afrag[NS][2];
  int fl = 0;
  if constexpr (MODE == 1) fl = *idxflag;

  if constexpr (MODE == 1) {
#pragma unroll
    for (int mt = 0; mt < 2; ++mt) {
      int e = R0 + w * 32 + mt * 16 + l16;
      e = e < Etot ? e : Etot - 1;
      int nd = fl ? eidx[2 * (Etot + e)] : eidx[Etot + e];  // dst (x_i, first half)
      int nsv = fl ? eidx[2 * e] : eidx[e];                 // src (x_j, second half)
      const short* pd = Asrc + (size_t)nd * HH;
      const short* ps = Asrc + (size_t)nsv * HH;
#pragma unroll
      for (int s = 0; s < 4; ++s) {
        afrag[s][mt] = *(const short8*)(pd + s * 32 + quad * 8);
        afrag[s + 4][mt] = *(const short8*)(ps + s * 32 + quad * 8);
      }
    }
  } else if constexpr (MODE == 2) {
#pragma unroll
    for (int mt = 0; mt < 2; ++mt) {
      int m = R0 + w * 32 + mt * 16 + l16;
      const short* pr = Asrc + (size_t)m * HH;
#pragma unroll
      for (int s = 0; s < 4; ++s) afrag[s][mt] = *(const short8*)(pr + s * 32 + quad * 8);
      const float* ar = aggin + (size_t)m * HH;
#pragma unroll
      for (int s = 0; s < 4; ++s) {
        floatx4 a0 = *(const floatx4*)(ar + s * 32 + quad * 8);
        floatx4 a1 = *(const floatx4*)(ar + s * 32 + quad * 8 + 4);
        short8 f;
        f[0] = f2bf(a0[0]); f[1] = f2bf(a0[1]); f[2] = f2bf(a0[2]); f[3] = f2bf(a0[3]);
        f[4] = f2bf(a1[0]); f[5] = f2bf(a1[1]); f[6] = f2bf(a1[2]); f[7] = f2bf(a1[3]);
        afrag[s + 4][mt] = f;
      }
    }
  } else {
    constexpr int ST = (MODE == 0) ? 64 : HH;
#pragma unroll
    for (int mt = 0; mt < 2; ++mt) {
      int m = R0 + w * 32 + mt * 16 + l16;
      const short* pr = Asrc + (size_t)m * ST;
#pragma unroll
      for (int s = 0; s < NS; ++s) afrag[s][mt] = *(const short8*)(pr + s * 32 + quad * 8);
    }
  }

  // bias preload (per n-tile, col = t*16 + l16), biases are canonical fp32
  float b1f[8], b2f[N2T];
#pragma unroll
  for (int t = 0; t < 8; ++t) b1f[t] = b1[t * 16 + l16];
#pragma unroll
  for (int t = 0; t < N2T; ++t) b2f[t] = b2[t * 16 + l16];

  __syncthreads();  // staging + gathers complete

  // --- GEMM1: hidden = A @ W1 ---
  floatx4 acc[2][8];
  floatx4 zero4 = {0.f, 0.f, 0.f, 0.f};
#pragma unroll
  for (int mt = 0; mt < 2; ++mt)
#pragma unroll
    for (int t = 0; t < 8; ++t) acc[mt][t] = zero4;

#pragma unroll
  for (int s = 0; s < NS; ++s) {
    short8 bfrag[8];
#pragma unroll
    for (int t = 0; t < 8; ++t)
      bfrag[t] = *(const short8*)(lds + (s * 8 + t) * 1024 + lane * 16);
#pragma unroll
    for (int mt = 0; mt < 2; ++mt)
#pragma unroll
      for (int t = 0; t < 8; ++t)
        acc[mt][t] = __builtin_amdgcn_mfma_f32_16x16x32_bf16(afrag[s][mt], bfrag[t], acc[mt][t], 0, 0, 0);
  }

  __syncthreads();  // W1T region dead

  // --- stage W2T swizzled into lds[32768:], wave w stages s2 = w ---
#pragma unroll
  for (int c = 0; c < N2T; ++c) {
    int n = c * 16 + l16, k = w * 32 + quad * 8;
    gl_lds16(W2T + n * HH + k, lds + 32768 + (w * N2T + c) * 1024 + lane * 16);
  }

  // --- hidden (bias+ReLU+bf16) -> swizzled A-slots in lds[0:32768] ---
  // slot(s2, mtg) lane l holds hidden[m=mtg*16+(l&15)][k=s2*32+(l>>4)*8 .. +8]
  const int mtgb = w * 2;
#pragma unroll
  for (int mt = 0; mt < 2; ++mt) {
#pragma unroll
    for (int nt = 0; nt < 8; ++nt) {
      floatx4 v = acc[mt][nt];
      int s2 = nt >> 1;
      int lpb = 16 * ((nt & 1) * 2 + (l16 >> 3));
      int joff = 2 * (l16 & 7);
      char* base = lds + (size_t)(s2 * 8 + mtgb + mt) * 1024 + joff;
#pragma unroll
      for (int r = 0; r < 4; ++r) {
        float h = v[r] + b1f[nt];
        h = h > 0.f ? h : 0.f;
        *(short*)(base + (quad * 4 + r + lpb) * 16) = f2bf(h);
      }
    }
  }

  __syncthreads();

  // --- GEMM2: out = hidden @ W2 ---
  floatx4 acc2[2][N2T];
#pragma unroll
  for (int mt = 0; mt < 2; ++mt)
#pragma unroll
    for (int t = 0; t < N2T; ++t) acc2[mt][t] = zero4;

#pragma unroll
  for (int s2 = 0; s2 < 4; ++s2) {
    short8 af[2];
#pragma unroll
    for (int mt = 0; mt < 2; ++mt)
      af[mt] = *(const short8*)(lds + (s2 * 8 + mtgb + mt) * 1024 + lane * 16);
    short8 bfr[N2T];
#pragma unroll
    for (int t = 0; t < N2T; ++t)
      bfr[t] = *(const short8*)(lds + 32768 + (s2 * N2T + t) * 1024 + lane * 16);
#pragma unroll
    for (int mt = 0; mt < 2; ++mt)
#pragma unroll
      for (int t = 0; t < N2T; ++t)
        acc2[mt][t] = __builtin_amdgcn_mfma_f32_16x16x32_bf16(af[mt], bfr[t], acc2[mt][t], 0, 0, 0);
  }

  // --- epilogue ---
  if constexpr (MODE == 1) {
#pragma unroll
    for (int mt = 0; mt < 2; ++mt) {
      int rb = R0 + w * 32 + mt * 16 + quad * 4;
      int dsts[4];
#pragma unroll
      for (int r = 0; r < 4; ++r) {
        int e = rb + r; e = e < Etot ? e : Etot - 1;
        dsts[r] = fl ? eidx[2 * (Etot + e)] : eidx[Etot + e];
      }
#pragma unroll
      for (int nt = 0; nt < 8; ++nt) {
        int col = nt * 16 + l16;
#pragma unroll
        for (int r = 0; r < 4; ++r) {
          if (rb + r < Etot)
            unsafeAtomicAdd(aggout + (size_t)dsts[r] * HH + col, acc2[mt][nt][r] + b2f[nt]);
        }
      }
    }
  } else if constexpr (MODE == 3) {
#pragma unroll
    for (int mt = 0; mt < 2; ++mt)
#pragma unroll
      for (int nt = 0; nt < N2T; ++nt) {
        int col = nt * 16 + l16;
#pragma unroll
        for (int r = 0; r < 4; ++r) {
          int row = R0 + w * 32 + mt * 16 + quad * 4 + r;
          outf[(size_t)row * 32 + col] = acc2[mt][nt][r] + b2f[nt];
        }
      }
  } else {
#pragma unroll
    for (int mt = 0; mt < 2; ++mt)
#pragma unroll
      for (int nt = 0; nt < 8; ++nt) {
        int col = nt * 16 + l16;
#pragma unroll
        for (int r = 0; r < 4; ++r) {
          int row = R0 + w * 32 + mt * 16 + quad * 4 + r;
          outbf[(size_t)row * HH + col] = f2bf(acc2[mt][nt][r] + b2f[nt]);
        }
      }
  }
}

// ---------------- loss ----------------

__global__ void loss_kernel(const float* __restrict__ out32, const float* __restrict__ locf,
                            const float* __restrict__ yf, float* __restrict__ out,
                            float* __restrict__ acc, int NB) {
  int i = blockIdx.x * 256 + threadIdx.x;
  const float* o = out32 + (size_t)i * 32;
  const float* lp = locf + (size_t)i * 30;
  const float* yp = yf + (size_t)i * 30;
  float dsum = 0.f, fde = 0.f;
#pragma unroll
  for (int f = 0; f < 10; ++f) {
    float dx = o[f * 3 + 0] + lp[f * 3 + 0] - yp[f * 3 + 0];
    float dy = o[f * 3 + 1] + lp[f * 3 + 1] - yp[f * 3 + 1];
    float dz = o[f * 3 + 2] + lp[f * 3 + 2] - yp[f * 3 + 2];
    float d = sqrtf(dx * dx + dy * dy + dz * dz);
    dsum += d;
    if (f == 9) fde = d;
  }
#pragma unroll
  for (int m = 1; m < 16; m <<= 1) {
    dsum += __shfl_xor(dsum, m);
    fde += __shfl_xor(fde, m);
  }
  if ((threadIdx.x & 15) == 0) {
    int b = i >> 4;
    out[1 + b] = dsum / 160.0f;
    out[1 + NB + b] = fde / 16.0f;
    unsafeAtomicAdd(acc, dsum);
  }
}

__global__ void final_kernel(const float* __restrict__ acc, float* __restrict__ out, float inv) {
  if (threadIdx.x == 0) out[0] = *acc * inv;
}

// ---------------- host ----------------

extern "C" void kernel_launch(void* const* d_in, const int* in_sizes, int n_in,
                              void* d_out, int out_size, void* d_ws, size_t ws_size,
                              hipStream_t stream) {
  const void* loc = d_in[0];
  const void* vel = d_in[1];
  const void* yv = d_in[2];
  const int* eidx = (const int*)d_in[3];
  const void* embW1 = d_in[5];
  const void* embB1 = d_in[6];
  const void* embW2 = d_in[7];
  const void* embB2 = d_in[8];
  const void* msgW1 = d_in[9];
  const void* msgB1 = d_in[10];
  const void* msgW2 = d_in[11];
  const void* msgB2 = d_in[12];
  const void* updW1 = d_in[13];
  const void* updB1 = d_in[14];
  const void* updW2 = d_in[15];
  const void* updB2 = d_in[16];
  const void* headW1 = d_in[17];
  const void* headB1 = d_in[18];
  const void* headW2 = d_in[19];
  const void* headB2 = d_in[20];

  const int N = in_sizes[0] / 30;  // 32768
  const int E = in_sizes[3] / 2;   // 524288
  const int L = 7;
  const int NB = N / 16;           // 2048 batch entries

  const size_t MB = 1024 * 1024;
  char* ws = (char*)d_ws;
  short* x = (short*)ws;                       // N*128 bf16  (8 MB)
  short* in64 = (short*)(ws + 8 * MB);         // N*64 bf16   (4 MB)
  float* agg = (float*)(ws + 12 * MB);         // N*128 f32   (16 MB)
  float* out32 = (float*)(ws + 28 * MB);       // N*32 f32    (4 MB)
  short* wbase = (short*)(ws + 32 * MB);
  short* embW1T = wbase;                  // 128*64
  short* embW2T = embW1T + 128 * 64;      // 128*128
  short* headW1T = embW2T + 128 * 128;    // 128*128
  short* headW2T = headW1T + 128 * 128;   // 32*128
  short* msgW1T = headW2T + 32 * 128;     // 7*128*256
  short* msgW2T = msgW1T + 7 * 128 * 256; // 7*128*128
  short* updW1T = msgW2T + 7 * 128 * 128; // 7*128*256
  short* updW2T = updW1T + 7 * 128 * 256; // 7*128*128
  float* bias = (float*)(ws + 34 * MB);
  float* embB1f = bias;            // 128
  float* embB2f = bias + 128;      // 128
  float* msgB1f = bias + 256;      // 896
  float* msgB2f = bias + 1152;     // 896
  float* updB1f = bias + 2048;     // 896
  float* updB2f = bias + 2944;     // 896
  float* headB1f = bias + 3840;    // 128
  float* headB2f = bias + 3968;    // 32 (30 + zero pad)
  float* locf = (float*)(ws + 35 * MB);  // N*30 f32 (3.75 MB)
  float* yf = (float*)(ws + 39 * MB);    // N*30 f32
  int* iflag = (int*)(ws + 43 * MB);
  int* dflag = (int*)(ws + 43 * MB + 64);
  float* accp = (float*)(ws + 43 * MB + 128);

  detect_idx<<<1, 256, 0, stream>>>(eidx, iflag);
  detect_dtype<<<1, 256, 0, stream>>>((const uint32_t*)loc, dflag);

  pad_input<<<(N * 64) / 256, 256, 0, stream>>>(loc, vel, in64, dflag);
  transpose_w<<<(1 * 128 * 64) / 256, 256, 0, stream>>>(embW1, embW1T, 1, 60, 128, 64, 128, dflag);
  transpose_w<<<(1 * 128 * 128) / 256, 256, 0, stream>>>(embW2, embW2T, 1, 128, 128, 128, 128, dflag);
  transpose_w<<<(1 * 128 * 128) / 256, 256, 0, stream>>>(headW1, headW1T, 1, 128, 128, 128, 128, dflag);
  transpose_w<<<(1 * 32 * 128) / 256, 256, 0, stream>>>(headW2, headW2T, 1, 128, 30, 128, 32, dflag);
  transpose_w<<<(7 * 128 * 256) / 256, 256, 0, stream>>>(msgW1, msgW1T, 7, 256, 128, 256, 128, dflag);
  transpose_w<<<(7 * 128 * 128) / 256, 256, 0, stream>>>(msgW2, msgW2T, 7, 128, 128, 128, 128, dflag);
  transpose_w<<<(7 * 128 * 256) / 256, 256, 0, stream>>>(updW1, updW1T, 7, 256, 128, 256, 128, dflag);
  transpose_w<<<(7 * 128 * 128) / 256, 256, 0, stream>>>(updW2, updW2T, 7, 128, 128, 128, 128, dflag);

  cvt_f32<<<1, 256, 0, stream>>>(embB1, embB1f, 128, 128, dflag);
  cvt_f32<<<1, 256, 0, stream>>>(embB2, embB2f, 128, 128, dflag);
  cvt_f32<<<4, 256, 0, stream>>>(msgB1, msgB1f, 896, 896, dflag);
  cvt_f32<<<4, 256, 0, stream>>>(msgB2, msgB2f, 896, 896, dflag);
  cvt_f32<<<4, 256, 0, stream>>>(updB1, updB1f, 896, 896, dflag);
  cvt_f32<<<4, 256, 0, stream>>>(updB2, updB2f, 896, 896, dflag);
  cvt_f32<<<1, 256, 0, stream>>>(headB1, headB1f, 128, 128, dflag);
  cvt_f32<<<1, 256, 0, stream>>>(headB2, headB2f, 30, 32, dflag);
  cvt_f32<<<(N * 30 + 255) / 256, 256, 0, stream>>>(loc, locf, N * 30, N * 30, dflag);
  cvt_f32<<<(N * 30 + 255) / 256, 256, 0, stream>>>(yv, yf, N * 30, N * 30, dflag);

  mlp2_kernel<0><<<N / 128, 256, 0, stream>>>(in64, nullptr, nullptr, nullptr,
      embW1T, embB1f, embW2T, embB2f, x, nullptr, nullptr, 0);

  for (int l = 0; l < L; ++l) {
    hipMemsetAsync(agg, 0, (size_t)N * HH * 4, stream);
    mlp2_kernel<1><<<(E + 127) / 128, 256, 0, stream>>>(x, nullptr, eidx, iflag,
        msgW1T + l * 128 * 256, msgB1f + l * 128, msgW2T + l * 128 * 128, msgB2f + l * 128,
        nullptr, agg, nullptr, E);
    mlp2_kernel<2><<<N / 128, 256, 0, stream>>>(x, agg, nullptr, nullptr,
        updW1T + l * 128 * 256, updB1f + l * 128, updW2T + l * 128 * 128, updB2f + l * 128,
        x, nullptr, nullptr, 0);
  }

  mlp2_kernel<3><<<N / 128, 256, 0, stream>>>(x, nullptr, nullptr, nullptr,
      headW1T, headB1f, headW2T, headB2f, nullptr, nullptr, out32, 0);

  hipMemsetAsync(accp, 0, 4, stream);
  loss_kernel<<<N / 256, 256, 0, stream>>>(out32, locf, yf, (float*)d_out, accp, NB);
  final_kernel<<<1, 64, 0, stream>>>(accp, (float*)d_out, 1.0f / 327680.0f);
}

// Round 3
// 694.904 us; speedup vs baseline: 2.8098x; 2.8098x over previous
//
#include <hip/hip_runtime.h>
#include <hip/hip_bf16.h>
#include <stdint.h>

#define HH 128

typedef __attribute__((ext_vector_type(8))) short short8;
typedef __attribute__((ext_vector_type(4))) float floatx4;

typedef __attribute__((address_space(3))) uint32_t lds_u32_t;
typedef const __attribute__((address_space(1))) uint32_t gbl_u32_t;

__device__ __forceinline__ void gl_lds16(const void* g, void* l) {
  __builtin_amdgcn_global_load_lds((gbl_u32_t*)g, (lds_u32_t*)l, 16, 0, 0);
}

__device__ __forceinline__ float bf2f(short v) {
  union { uint32_t u; float f; } x; x.u = ((uint32_t)(uint16_t)v) << 16; return x.f;
}
__device__ __forceinline__ short f2bf(float f) {
  union { float f; uint32_t u; } x; x.f = f;
  uint32_t r = x.u + 0x7fffu + ((x.u >> 16) & 1u);
  return (short)(r >> 16);
}
__device__ __forceinline__ float rdf(const void* p, int i, int fl) {
  return fl ? bf2f(((const short*)p)[i]) : ((const float*)p)[i];
}

// ---------------- probes ----------------

__global__ void detect_idx(const int* __restrict__ eidx, int* flag) {
  __shared__ int nz;
  if (threadIdx.x == 0) nz = 0;
  __syncthreads();
  int any = 0;
  for (int i = threadIdx.x; i < 1024; i += 256) any |= (eidx[2 * i + 1] != 0);
  if (any) atomicOr(&nz, 1);
  __syncthreads();
  if (threadIdx.x == 0) *flag = (nz == 0) ? 1 : 0;  // 1 => int64 layout
}

__global__ void detect_dtype(const uint32_t* __restrict__ p, int* dflag) {
  __shared__ int cnt;
  if (threadIdx.x == 0) cnt = 0;
  __syncthreads();
  uint32_t u = p[threadIdx.x];
  int e = (u >> 7) & 0xFF;
  if (e >= 100 && e <= 140) atomicAdd(&cnt, 1);
  __syncthreads();
  if (threadIdx.x == 0) *dflag = (cnt >= 192) ? 1 : 0;  // 1 => bf16
}

// ---------------- prep kernels ----------------

__global__ void pad_input(const void* __restrict__ loc, const void* __restrict__ vel,
                          short* __restrict__ dst, const int* __restrict__ dflag) {
  int fl = *dflag;
  int idx = blockIdx.x * 256 + threadIdx.x;
  int j = idx & 63, i = idx >> 6;
  short v = 0;
  if (j < 60) {
    int f = j / 6, c = j % 6;
    float x = (c < 3) ? rdf(loc, (i * 10 + f) * 3 + c, fl)
                      : rdf(vel, (i * 10 + f) * 3 + (c - 3), fl);
    v = f2bf(x);
  }
  dst[idx] = v;
}

__global__ void transpose_w(const void* __restrict__ src, short* __restrict__ dst,
                            int L, int K, int N, int Kp, int Np,
                            const int* __restrict__ dflag) {
  int fl = *dflag;
  int idx = blockIdx.x * 256 + threadIdx.x;
  int tot = L * Np * Kp;
  if (idx >= tot) return;
  int k = idx % Kp; int rest = idx / Kp; int n = rest % Np; int l = rest / Np;
  short v = 0;
  if (k < K && n < N) v = f2bf(rdf(src, (l * K + k) * N + n, fl));
  dst[idx] = v;
}

__global__ void cvt_f32(const void* __restrict__ src, float* __restrict__ dst,
                        int n, int npad, const int* __restrict__ dflag) {
  int fl = *dflag;
  int i = blockIdx.x * 256 + threadIdx.x;
  if (i < npad) dst[i] = (i < n) ? rdf(src, i, fl) : 0.0f;
}

// ---------------- edge sort (counting sort by dst) ----------------

__global__ void hist_kernel(const int* __restrict__ eidx, const int* __restrict__ iflag,
                            int* __restrict__ counts, int E) {
  int e = blockIdx.x * 256 + threadIdx.x;
  if (e >= E) return;
  int fl = *iflag;
  int d = fl ? eidx[2 * (E + e)] : eidx[E + e];
  atomicAdd(&counts[d], 1);
}

// single block, 1024 threads; N up to 32*1024
__global__ void scan_kernel(const int* __restrict__ counts, int* __restrict__ row_start,
                            int* __restrict__ cursor, float* __restrict__ deg,
                            int N, int E) {
  __shared__ int partial[1024];
  int t = threadIdx.x;
  int chunk = (N + 1023) >> 10;
  int base = t * chunk;
  int s = 0;
  for (int i = 0; i < chunk; ++i) {
    int idx = base + i;
    if (idx < N) s += counts[idx];
  }
  partial[t] = s;
  __syncthreads();
  for (int off = 1; off < 1024; off <<= 1) {
    int v = 0;
    if (t >= off) v = partial[t - off];
    __syncthreads();
    partial[t] += v;
    __syncthreads();
  }
  int run = partial[t] - s;  // exclusive prefix
  for (int i = 0; i < chunk; ++i) {
    int idx = base + i;
    if (idx < N) {
      int c = counts[idx];
      row_start[idx] = run;
      cursor[idx] = run;
      deg[idx] = (float)c;
      run += c;
    }
  }
  if (t == 1023) row_start[N] = E;
}

__global__ void scatter_kernel(const int* __restrict__ eidx, const int* __restrict__ iflag,
                               int* __restrict__ cursor, int* __restrict__ ssrc, int E) {
  int e = blockIdx.x * 256 + threadIdx.x;
  if (e >= E) return;
  int fl = *iflag;
  int d = fl ? eidx[2 * (E + e)] : eidx[E + e];
  int sv = fl ? eidx[2 * e] : eidx[e];
  int pos = atomicAdd(&cursor[d], 1);
  ssrc[pos] = sv;
}

// ---------------- P/Q GEMM: P = x@W1a + b1 (fp32), Q = x@W1b (bf16) ----------------

__global__ __launch_bounds__(256, 2)
void gemm_pq(const short* __restrict__ x, const short* __restrict__ W1T,
             const float* __restrict__ b1, float* __restrict__ P, short* __restrict__ Qs) {
  __shared__ __align__(16) char lds[65536];
  const int tid = threadIdx.x;
  const int w = tid >> 6, lane = tid & 63;
  const int quad = lane >> 4, l16 = lane & 15;
  const int R0 = blockIdx.x * 128;

  // stage both halves of W1T (Kp=256): mat 0 = dst-side (k<128), mat 1 = src-side
#pragma unroll
  for (int c = 0; c < 16; ++c) {
    int slot = w * 16 + c;
    int mat = slot >> 5, id = slot & 31;
    int s = id >> 3, t = id & 7;
    int n = t * 16 + l16, k = s * 32 + quad * 8;
    gl_lds16(W1T + n * 256 + mat * 128 + k, lds + mat * 32768 + id * 1024 + lane * 16);
  }

  short8 afrag[4][2];
#pragma unroll
  for (int mt = 0; mt < 2; ++mt) {
    int m = R0 + w * 32 + mt * 16 + l16;
    const short* pr = x + (size_t)m * HH;
#pragma unroll
    for (int s = 0; s < 4; ++s) afrag[s][mt] = *(const short8*)(pr + s * 32 + quad * 8);
  }

  float b1f[8];
#pragma unroll
  for (int t = 0; t < 8; ++t) b1f[t] = b1[t * 16 + l16];

  __syncthreads();

  floatx4 zero4 = {0.f, 0.f, 0.f, 0.f};
  // --- P = x @ W1a ---
  {
    floatx4 acc[2][8];
#pragma unroll
    for (int mt = 0; mt < 2; ++mt)
#pragma unroll
      for (int t = 0; t < 8; ++t) acc[mt][t] = zero4;
#pragma unroll
    for (int s = 0; s < 4; ++s) {
      short8 bfrag[8];
#pragma unroll
      for (int t = 0; t < 8; ++t)
        bfrag[t] = *(const short8*)(lds + (s * 8 + t) * 1024 + lane * 16);
#pragma unroll
      for (int mt = 0; mt < 2; ++mt)
#pragma unroll
        for (int t = 0; t < 8; ++t)
          acc[mt][t] = __builtin_amdgcn_mfma_f32_16x16x32_bf16(afrag[s][mt], bfrag[t], acc[mt][t], 0, 0, 0);
    }
#pragma unroll
    for (int mt = 0; mt < 2; ++mt)
#pragma unroll
      for (int nt = 0; nt < 8; ++nt) {
        int col = nt * 16 + l16;
#pragma unroll
        for (int r = 0; r < 4; ++r) {
          int row = R0 + w * 32 + mt * 16 + quad * 4 + r;
          P[(size_t)row * HH + col] = acc[mt][nt][r] + b1f[nt];
        }
      }
  }
  // --- Q = x @ W1b ---
  {
    floatx4 acc[2][8];
#pragma unroll
    for (int mt = 0; mt < 2; ++mt)
#pragma unroll
      for (int t = 0; t < 8; ++t) acc[mt][t] = zero4;
#pragma unroll
    for (int s = 0; s < 4; ++s) {
      short8 bfrag[8];
#pragma unroll
      for (int t = 0; t < 8; ++t)
        bfrag[t] = *(const short8*)(lds + 32768 + (s * 8 + t) * 1024 + lane * 16);
#pragma unroll
      for (int mt = 0; mt < 2; ++mt)
#pragma unroll
        for (int t = 0; t < 8; ++t)
          acc[mt][t] = __builtin_amdgcn_mfma_f32_16x16x32_bf16(afrag[s][mt], bfrag[t], acc[mt][t], 0, 0, 0);
    }
#pragma unroll
    for (int mt = 0; mt < 2; ++mt)
#pragma unroll
      for (int nt = 0; nt < 8; ++nt) {
        int col = nt * 16 + l16;
#pragma unroll
        for (int r = 0; r < 4; ++r) {
          int row = R0 + w * 32 + mt * 16 + quad * 4 + r;
          Qs[(size_t)row * HH + col] = f2bf(acc[mt][nt][r]);
        }
      }
  }
}

// ---------------- edge aggregation: Hagg[d] = sum relu(P[d] + Q[src]) ----------------

__global__ __launch_bounds__(256)
void edge_agg(const float* __restrict__ P, const uint32_t* __restrict__ Qp,
              const int* __restrict__ ssrc, const int* __restrict__ row_start,
              uint32_t* __restrict__ Hagg, int Ntot) {
  int w = threadIdx.x >> 6, lane = threadIdx.x & 63;
  int d = blockIdx.x * 4 + w;
  if (d >= Ntot) return;
  float px = P[(size_t)d * HH + 2 * lane];
  float py = P[(size_t)d * HH + 2 * lane + 1];
  int s0 = row_start[d], s1 = row_start[d + 1];
  float ax = 0.f, ay = 0.f;
  int e = s0;
  for (; e + 4 <= s1; e += 4) {
    int i0 = ssrc[e], i1 = ssrc[e + 1], i2 = ssrc[e + 2], i3 = ssrc[e + 3];
    uint32_t q0 = Qp[(size_t)i0 * 64 + lane];
    uint32_t q1 = Qp[(size_t)i1 * 64 + lane];
    uint32_t q2 = Qp[(size_t)i2 * 64 + lane];
    uint32_t q3 = Qp[(size_t)i3 * 64 + lane];
    float hx, hy;
    hx = px + bf2f((short)(q0 & 0xffff)); hy = py + bf2f((short)(q0 >> 16));
    ax += hx > 0.f ? hx : 0.f; ay += hy > 0.f ? hy : 0.f;
    hx = px + bf2f((short)(q1 & 0xffff)); hy = py + bf2f((short)(q1 >> 16));
    ax += hx > 0.f ? hx : 0.f; ay += hy > 0.f ? hy : 0.f;
    hx = px + bf2f((short)(q2 & 0xffff)); hy = py + bf2f((short)(q2 >> 16));
    ax += hx > 0.f ? hx : 0.f; ay += hy > 0.f ? hy : 0.f;
    hx = px + bf2f((short)(q3 & 0xffff)); hy = py + bf2f((short)(q3 >> 16));
    ax += hx > 0.f ? hx : 0.f; ay += hy > 0.f ? hy : 0.f;
  }
  for (; e < s1; ++e) {
    int i0 = ssrc[e];
    uint32_t q0 = Qp[(size_t)i0 * 64 + lane];
    float hx = px + bf2f((short)(q0 & 0xffff));
    float hy = py + bf2f((short)(q0 >> 16));
    ax += hx > 0.f ? hx : 0.f;
    ay += hy > 0.f ? hy : 0.f;
  }
  uint32_t packed = (uint32_t)(uint16_t)f2bf(ax) | ((uint32_t)(uint16_t)f2bf(ay) << 16);
  Hagg[(size_t)d * 64 + lane] = packed;
}

// ---------------- agg GEMM: agg = Hagg @ W2 + deg*b2 (bf16 out) ----------------

__global__ __launch_bounds__(256, 2)
void gemm_agg(const short* __restrict__ Hagg, const short* __restrict__ W2T,
              const float* __restrict__ b2, const float* __restrict__ deg,
              short* __restrict__ aggbf) {
  __shared__ __align__(16) char lds[32768];
  const int tid = threadIdx.x;
  const int w = tid >> 6, lane = tid & 63;
  const int quad = lane >> 4, l16 = lane & 15;
  const int R0 = blockIdx.x * 128;

#pragma unroll
  for (int c = 0; c < 8; ++c) {
    int slot = w * 8 + c;
    int s = slot >> 3, t = slot & 7;
    int n = t * 16 + l16, k = s * 32 + quad * 8;
    gl_lds16(W2T + n * HH + k, lds + slot * 1024 + lane * 16);
  }

  short8 afrag[4][2];
#pragma unroll
  for (int mt = 0; mt < 2; ++mt) {
    int m = R0 + w * 32 + mt * 16 + l16;
    const short* pr = Hagg + (size_t)m * HH;
#pragma unroll
    for (int s = 0; s < 4; ++s) afrag[s][mt] = *(const short8*)(pr + s * 32 + quad * 8);
  }

  float b2f[8];
#pragma unroll
  for (int t = 0; t < 8; ++t) b2f[t] = b2[t * 16 + l16];

  __syncthreads();

  floatx4 zero4 = {0.f, 0.f, 0.f, 0.f};
  floatx4 acc[2][8];
#pragma unroll
  for (int mt = 0; mt < 2; ++mt)
#pragma unroll
    for (int t = 0; t < 8; ++t) acc[mt][t] = zero4;
#pragma unroll
  for (int s = 0; s < 4; ++s) {
    short8 bfrag[8];
#pragma unroll
    for (int t = 0; t < 8; ++t)
      bfrag[t] = *(const short8*)(lds + (s * 8 + t) * 1024 + lane * 16);
#pragma unroll
    for (int mt = 0; mt < 2; ++mt)
#pragma unroll
      for (int t = 0; t < 8; ++t)
        acc[mt][t] = __builtin_amdgcn_mfma_f32_16x16x32_bf16(afrag[s][mt], bfrag[t], acc[mt][t], 0, 0, 0);
  }

#pragma unroll
  for (int mt = 0; mt < 2; ++mt) {
#pragma unroll
    for (int r = 0; r < 4; ++r) {
      int row = R0 + w * 32 + mt * 16 + quad * 4 + r;
      float dv = deg[row];
#pragma unroll
      for (int nt = 0; nt < 8; ++nt) {
        int col = nt * 16 + l16;
        aggbf[(size_t)row * HH + col] = f2bf(acc[mt][nt][r] + dv * b2f[nt]);
      }
    }
  }
}

// ---------------- fused 2-layer MLP kernel (MODE: 0=EMBED 2=UPD 3=HEAD) ----------------

template <int MODE>
__global__ __launch_bounds__(256, 2)
void mlp2_kernel(const short* __restrict__ Asrc, const short* __restrict__ Asrc2,
                 const short* __restrict__ W1T, const float* __restrict__ b1,
                 const short* __restrict__ W2T, const float* __restrict__ b2,
                 short* __restrict__ outbf, float* __restrict__ outf) {
  constexpr int K1 = (MODE == 0) ? 64 : (MODE == 3) ? 128 : 256;
  constexpr int NS = K1 / 32;
  constexpr int N2T = (MODE == 3) ? 2 : 8;

  __shared__ __align__(16) char lds[65536];

  const int tid = threadIdx.x;
  const int w = tid >> 6, lane = tid & 63;
  const int quad = lane >> 4, l16 = lane & 15;
  const int R0 = blockIdx.x * 128;

#pragma unroll
  for (int c = 0; c < NS * 2; ++c) {
    int slot = w * (NS * 2) + c;
    int s = slot >> 3, t = slot & 7;
    int n = t * 16 + l16, k = s * 32 + quad * 8;
    gl_lds16(W1T + n * K1 + k, lds + slot * 1024 + lane * 16);
  }

  short8 afrag[NS][2];
  if constexpr (MODE == 2) {
#pragma unroll
    for (int mt = 0; mt < 2; ++mt) {
      int m = R0 + w * 32 + mt * 16 + l16;
      const short* pr = Asrc + (size_t)m * HH;
      const short* ar = Asrc2 + (size_t)m * HH;
#pragma unroll
      for (int s = 0; s < 4; ++s) {
        afrag[s][mt] = *(const short8*)(pr + s * 32 + quad * 8);
        afrag[s + 4][mt] = *(const short8*)(ar + s * 32 + quad * 8);
      }
    }
  } else {
    constexpr int ST = (MODE == 0) ? 64 : HH;
#pragma unroll
    for (int mt = 0; mt < 2; ++mt) {
      int m = R0 + w * 32 + mt * 16 + l16;
      const short* pr = Asrc + (size_t)m * ST;
#pragma unroll
      for (int s = 0; s < NS; ++s) afrag[s][mt] = *(const short8*)(pr + s * 32 + quad * 8);
    }
  }

  float b1f[8], b2f[N2T];
#pragma unroll
  for (int t = 0; t < 8; ++t) b1f[t] = b1[t * 16 + l16];
#pragma unroll
  for (int t = 0; t < N2T; ++t) b2f[t] = b2[t * 16 + l16];

  __syncthreads();

  floatx4 acc[2][8];
  floatx4 zero4 = {0.f, 0.f, 0.f, 0.f};
#pragma unroll
  for (int mt = 0; mt < 2; ++mt)
#pragma unroll
    for (int t = 0; t < 8; ++t) acc[mt][t] = zero4;

#pragma unroll
  for (int s = 0; s < NS; ++s) {
    short8 bfrag[8];
#pragma unroll
    for (int t = 0; t < 8; ++t)
      bfrag[t] = *(const short8*)(lds + (s * 8 + t) * 1024 + lane * 16);
#pragma unroll
    for (int mt = 0; mt < 2; ++mt)
#pragma unroll
      for (int t = 0; t < 8; ++t)
        acc[mt][t] = __builtin_amdgcn_mfma_f32_16x16x32_bf16(afrag[s][mt], bfrag[t], acc[mt][t], 0, 0, 0);
  }

  __syncthreads();

#pragma unroll
  for (int c = 0; c < N2T; ++c) {
    int n = c * 16 + l16, k = w * 32 + quad * 8;
    gl_lds16(W2T + n * HH + k, lds + 32768 + (w * N2T + c) * 1024 + lane * 16);
  }

  const int mtgb = w * 2;
#pragma unroll
  for (int mt = 0; mt < 2; ++mt) {
#pragma unroll
    for (int nt = 0; nt < 8; ++nt) {
      floatx4 v = acc[mt][nt];
      int s2 = nt >> 1;
      int lpb = 16 * ((nt & 1) * 2 + (l16 >> 3));
      int joff = 2 * (l16 & 7);
      char* base = lds + (size_t)(s2 * 8 + mtgb + mt) * 1024 + joff;
#pragma unroll
      for (int r = 0; r < 4; ++r) {
        float h = v[r] + b1f[nt];
        h = h > 0.f ? h : 0.f;
        *(short*)(base + (quad * 4 + r + lpb) * 16) = f2bf(h);
      }
    }
  }

  __syncthreads();

  floatx4 acc2[2][N2T];
#pragma unroll
  for (int mt = 0; mt < 2; ++mt)
#pragma unroll
    for (int t = 0; t < N2T; ++t) acc2[mt][t] = zero4;

#pragma unroll
  for (int s2 = 0; s2 < 4; ++s2) {
    short8 af[2];
#pragma unroll
    for (int mt = 0; mt < 2; ++mt)
      af[mt] = *(const short8*)(lds + (s2 * 8 + mtgb + mt) * 1024 + lane * 16);
    short8 bfr[N2T];
#pragma unroll
    for (int t = 0; t < N2T; ++t)
      bfr[t] = *(const short8*)(lds + 32768 + (s2 * N2T + t) * 1024 + lane * 16);
#pragma unroll
    for (int mt = 0; mt < 2; ++mt)
#pragma unroll
      for (int t = 0; t < N2T; ++t)
        acc2[mt][t] = __builtin_amdgcn_mfma_f32_16x16x32_bf16(af[mt], bfr[t], acc2[mt][t], 0, 0, 0);
  }

  if constexpr (MODE == 3) {
#pragma unroll
    for (int mt = 0; mt < 2; ++mt)
#pragma unroll
      for (int nt = 0; nt < N2T; ++nt) {
        int col = nt * 16 + l16;
#pragma unroll
        for (int r = 0; r < 4; ++r) {
          int row = R0 + w * 32 + mt * 16 + quad * 4 + r;
          outf[(size_t)row * 32 + col] = acc2[mt][nt][r] + b2f[nt];
        }
      }
  } else {
#pragma unroll
    for (int mt = 0; mt < 2; ++mt)
#pragma unroll
      for (int nt = 0; nt < 8; ++nt) {
        int col = nt * 16 + l16;
#pragma unroll
        for (int r = 0; r < 4; ++r) {
          int row = R0 + w * 32 + mt * 16 + quad * 4 + r;
          outbf[(size_t)row * HH + col] = f2bf(acc2[mt][nt][r] + b2f[nt]);
        }
      }
  }
}

// ---------------- loss ----------------

__global__ void loss_kernel(const float* __restrict__ out32, const void* __restrict__ loc,
                            const void* __restrict__ yv, const int* __restrict__ dflag,
                            float* __restrict__ out, float* __restrict__ acc, int NB) {
  int fl = *dflag;
  int i = blockIdx.x * 256 + threadIdx.x;
  const float* o = out32 + (size_t)i * 32;
  float dsum = 0.f, fde = 0.f;
#pragma unroll
  for (int f = 0; f < 10; ++f) {
    float dx = o[f * 3 + 0] + rdf(loc, i * 30 + f * 3 + 0, fl) - rdf(yv, i * 30 + f * 3 + 0, fl);
    float dy = o[f * 3 + 1] + rdf(loc, i * 30 + f * 3 + 1, fl) - rdf(yv, i * 30 + f * 3 + 1, fl);
    float dz = o[f * 3 + 2] + rdf(loc, i * 30 + f * 3 + 2, fl) - rdf(yv, i * 30 + f * 3 + 2, fl);
    float d = sqrtf(dx * dx + dy * dy + dz * dz);
    dsum += d;
    if (f == 9) fde = d;
  }
#pragma unroll
  for (int m = 1; m < 16; m <<= 1) {
    dsum += __shfl_xor(dsum, m);
    fde += __shfl_xor(fde, m);
  }
  if ((threadIdx.x & 15) == 0) {
    int b = i >> 4;
    out[1 + b] = dsum / 160.0f;
    out[1 + NB + b] = fde / 16.0f;
    unsafeAtomicAdd(acc, dsum);
  }
}

__global__ void final_kernel(const float* __restrict__ acc, float* __restrict__ out, float inv) {
  if (threadIdx.x == 0) out[0] = *acc * inv;
}

// ---------------- host ----------------

extern "C" void kernel_launch(void* const* d_in, const int* in_sizes, int n_in,
                              void* d_out, int out_size, void* d_ws, size_t ws_size,
                              hipStream_t stream) {
  const void* loc = d_in[0];
  const void* vel = d_in[1];
  const void* yv = d_in[2];
  const int* eidx = (const int*)d_in[3];
  const void* embW1 = d_in[5];
  const void* embB1 = d_in[6];
  const void* embW2 = d_in[7];
  const void* embB2 = d_in[8];
  const void* msgW1 = d_in[9];
  const void* msgB1 = d_in[10];
  const void* msgW2 = d_in[11];
  const void* msgB2 = d_in[12];
  const void* updW1 = d_in[13];
  const void* updB1 = d_in[14];
  const void* updW2 = d_in[15];
  const void* updB2 = d_in[16];
  const void* headW1 = d_in[17];
  const void* headB1 = d_in[18];
  const void* headW2 = d_in[19];
  const void* headB2 = d_in[20];

  const int N = in_sizes[0] / 30;  // 32768
  const int E = in_sizes[3] / 2;   // 524288
  const int L = 7;
  const int NB = N / 16;

  const size_t MB = 1024 * 1024;
  char* ws = (char*)d_ws;
  short* x = (short*)ws;                     // N*128 bf16   [0,8)MB
  float* P = (float*)(ws + 8 * MB);          // N*128 f32    [8,24)MB
  short* in64 = (short*)(ws + 8 * MB);       // overlays P head (consumed before P written)
  short* Qs = (short*)(ws + 24 * MB);        // N*128 bf16   [24,32)MB
  short* Hagg = (short*)(ws + 32 * MB);      // N*128 bf16   [32,40)MB
  float* out32 = (float*)(ws + 32 * MB);     // overlays Hagg (used after layers)
  short* aggbf = (short*)(ws + 40 * MB);     // N*128 bf16   [40,48)MB
  short* wbase = (short*)(ws + 48 * MB);     // ~1.5MB of transposed weights
  short* embW1T = wbase;                     // 128*64
  short* embW2T = embW1T + 128 * 64;         // 128*128
  short* headW1T = embW2T + 128 * 128;       // 128*128
  short* headW2T = headW1T + 128 * 128;      // 32*128
  short* msgW1T = headW2T + 32 * 128;        // 7*128*256
  short* msgW2T = msgW1T + 7 * 128 * 256;    // 7*128*128
  short* updW1T = msgW2T + 7 * 128 * 128;    // 7*128*256
  short* updW2T = updW1T + 7 * 128 * 256;    // 7*128*128
  float* bias = (float*)(ws + 49 * MB + 512 * 1024);  // 16KB of fp32 biases
  float* embB1f = bias;
  float* embB2f = bias + 128;
  float* msgB1f = bias + 256;
  float* msgB2f = bias + 1152;
  float* updB1f = bias + 2048;
  float* updB2f = bias + 2944;
  float* headB1f = bias + 3840;
  float* headB2f = bias + 3968;
  int* counts = (int*)(ws + 49 * MB + 768 * 1024);     // N ints
  int* row_start = (int*)(ws + 50 * MB);               // N+1 ints
  int* cursor = (int*)(ws + 50 * MB + 256 * 1024);     // N ints
  float* deg = (float*)(ws + 50 * MB + 512 * 1024);    // N floats
  int* iflag = (int*)(ws + 50 * MB + 768 * 1024);
  int* dflag = iflag + 16;
  float* accp = (float*)(iflag + 32);
  int* ssrc = (int*)(ws + 51 * MB);                    // E ints [51,53)MB

  detect_idx<<<1, 256, 0, stream>>>(eidx, iflag);
  detect_dtype<<<1, 256, 0, stream>>>((const uint32_t*)loc, dflag);

  // edge sort by dst
  hipMemsetAsync(counts, 0, (size_t)N * 4, stream);
  hist_kernel<<<(E + 255) / 256, 256, 0, stream>>>(eidx, iflag, counts, E);
  scan_kernel<<<1, 1024, 0, stream>>>(counts, row_start, cursor, deg, N, E);
  scatter_kernel<<<(E + 255) / 256, 256, 0, stream>>>(eidx, iflag, cursor, ssrc, E);

  pad_input<<<(N * 64) / 256, 256, 0, stream>>>(loc, vel, in64, dflag);
  transpose_w<<<(1 * 128 * 64) / 256, 256, 0, stream>>>(embW1, embW1T, 1, 60, 128, 64, 128, dflag);
  transpose_w<<<(1 * 128 * 128) / 256, 256, 0, stream>>>(embW2, embW2T, 1, 128, 128, 128, 128, dflag);
  transpose_w<<<(1 * 128 * 128) / 256, 256, 0, stream>>>(headW1, headW1T, 1, 128, 128, 128, 128, dflag);
  transpose_w<<<(1 * 32 * 128) / 256, 256, 0, stream>>>(headW2, headW2T, 1, 128, 30, 128, 32, dflag);
  transpose_w<<<(7 * 128 * 256) / 256, 256, 0, stream>>>(msgW1, msgW1T, 7, 256, 128, 256, 128, dflag);
  transpose_w<<<(7 * 128 * 128) / 256, 256, 0, stream>>>(msgW2, msgW2T, 7, 128, 128, 128, 128, dflag);
  transpose_w<<<(7 * 128 * 256) / 256, 256, 0, stream>>>(updW1, updW1T, 7, 256, 128, 256, 128, dflag);
  transpose_w<<<(7 * 128 * 128) / 256, 256, 0, stream>>>(updW2, updW2T, 7, 128, 128, 128, 128, dflag);

  cvt_f32<<<1, 256, 0, stream>>>(embB1, embB1f, 128, 128, dflag);
  cvt_f32<<<1, 256, 0, stream>>>(embB2, embB2f, 128, 128, dflag);
  cvt_f32<<<4, 256, 0, stream>>>(msgB1, msgB1f, 896, 896, dflag);
  cvt_f32<<<4, 256, 0, stream>>>(msgB2, msgB2f, 896, 896, dflag);
  cvt_f32<<<4, 256, 0, stream>>>(updB1, updB1f, 896, 896, dflag);
  cvt_f32<<<4, 256, 0, stream>>>(updB2, updB2f, 896, 896, dflag);
  cvt_f32<<<1, 256, 0, stream>>>(headB1, headB1f, 128, 128, dflag);
  cvt_f32<<<1, 256, 0, stream>>>(headB2, headB2f, 30, 32, dflag);

  mlp2_kernel<0><<<N / 128, 256, 0, stream>>>(in64, nullptr,
      embW1T, embB1f, embW2T, embB2f, x, nullptr);

  for (int l = 0; l < L; ++l) {
    gemm_pq<<<N / 128, 256, 0, stream>>>(x, msgW1T + l * 128 * 256, msgB1f + l * 128, P, Qs);
    edge_agg<<<(N + 3) / 4, 256, 0, stream>>>(P, (const uint32_t*)Qs, ssrc, row_start,
                                              (uint32_t*)Hagg, N);
    gemm_agg<<<N / 128, 256, 0, stream>>>(Hagg, msgW2T + l * 128 * 128, msgB2f + l * 128,
                                          deg, aggbf);
    mlp2_kernel<2><<<N / 128, 256, 0, stream>>>(x, aggbf,
        updW1T + l * 128 * 256, updB1f + l * 128, updW2T + l * 128 * 128, updB2f + l * 128,
        x, nullptr);
  }

  mlp2_kernel<3><<<N / 128, 256, 0, stream>>>(x, nullptr,
      headW1T, headB1f, headW2T, headB2f, nullptr, out32);

  hipMemsetAsync(accp, 0, 4, stream);
  loss_kernel<<<N / 256, 256, 0, stream>>>(out32, loc, yv, dflag, (float*)d_out, accp, NB);
  final_kernel<<<1, 64, 0, stream>>>(accp, (float*)d_out, 1.0f / 327680.0f);
}

// Round 4
// 573.216 us; speedup vs baseline: 3.4063x; 1.2123x over previous
//
#include <hip/hip_runtime.h>
#include <hip/hip_bf16.h>
#include <stdint.h>

#define HH 128

typedef __attribute__((ext_vector_type(8))) short short8;
typedef __attribute__((ext_vector_type(4))) float floatx4;

typedef __attribute__((address_space(3))) uint32_t lds_u32_t;
typedef const __attribute__((address_space(1))) uint32_t gbl_u32_t;

__device__ __forceinline__ void gl_lds16(const void* g, void* l) {
  __builtin_amdgcn_global_load_lds((gbl_u32_t*)g, (lds_u32_t*)l, 16, 0, 0);
}

__device__ __forceinline__ float bf2f(short v) {
  union { uint32_t u; float f; } x; x.u = ((uint32_t)(uint16_t)v) << 16; return x.f;
}
__device__ __forceinline__ short f2bf(float f) {
  union { float f; uint32_t u; } x; x.f = f;
  uint32_t r = x.u + 0x7fffu + ((x.u >> 16) & 1u);
  return (short)(r >> 16);
}
__device__ __forceinline__ float rdf(const void* p, int i, int fl) {
  return fl ? bf2f(((const short*)p)[i]) : ((const float*)p)[i];
}

// ---------------- probes ----------------

__global__ void detect_idx(const int* __restrict__ eidx, int* flag) {
  __shared__ int nz;
  if (threadIdx.x == 0) nz = 0;
  __syncthreads();
  int any = 0;
  for (int i = threadIdx.x; i < 1024; i += 256) any |= (eidx[2 * i + 1] != 0);
  if (any) atomicOr(&nz, 1);
  __syncthreads();
  if (threadIdx.x == 0) *flag = (nz == 0) ? 1 : 0;  // 1 => int64 layout
}

__global__ void detect_dtype(const uint32_t* __restrict__ p, int* dflag) {
  __shared__ int cnt;
  if (threadIdx.x == 0) cnt = 0;
  __syncthreads();
  uint32_t u = p[threadIdx.x];
  int e = (u >> 7) & 0xFF;
  if (e >= 100 && e <= 140) atomicAdd(&cnt, 1);
  __syncthreads();
  if (threadIdx.x == 0) *dflag = (cnt >= 192) ? 1 : 0;  // 1 => bf16
}

// ---------------- merged prep kernels ----------------

__global__ void pad_input(const void* __restrict__ loc, const void* __restrict__ vel,
                          short* __restrict__ dst, const int* __restrict__ dflag) {
  int fl = *dflag;
  int idx = blockIdx.x * 256 + threadIdx.x;
  int j = idx & 63, i = idx >> 6;
  short v = 0;
  if (j < 60) {
    int f = j / 6, c = j % 6;
    float x = (c < 3) ? rdf(loc, (i * 10 + f) * 3 + c, fl)
                      : rdf(vel, (i * 10 + f) * 3 + (c - 3), fl);
    v = f2bf(x);
  }
  dst[idx] = v;
}

struct WPrep {
  const void* src[8];
  unsigned long long dstoff[8];
  int L[8], K[8], Nn[8], Kp[8], Np[8];
  int bstart[9];
};

// src (L,K,N) row-major -> wbase+dstoff as (L,Np,Kp) row-major bf16 (transpose+pad)
__global__ void prep_w(WPrep a, short* __restrict__ wbase, const int* __restrict__ dflag) {
  int fl = *dflag;
  int b = blockIdx.x;
  int s = 0;
  while (b >= a.bstart[s + 1]) ++s;
  int idx = (b - a.bstart[s]) * 256 + threadIdx.x;
  int Kp = a.Kp[s], Np = a.Np[s], K = a.K[s], Nn = a.Nn[s];
  int tot = a.L[s] * Np * Kp;
  if (idx >= tot) return;
  int k = idx % Kp; int rest = idx / Kp; int n = rest % Np; int l = rest / Np;
  short v = 0;
  if (k < K && n < Nn) v = f2bf(rdf(a.src[s], (l * K + k) * Nn + n, fl));
  wbase[a.dstoff[s] + idx] = v;
}

struct BPrep {
  const void* src[8];
  int n[8];
  int estart[9];
};

__global__ void prep_b(BPrep a, float* __restrict__ bias, const int* __restrict__ dflag) {
  int fl = *dflag;
  int idx = blockIdx.x * 256 + threadIdx.x;
  if (idx >= a.estart[8]) return;
  int s = 0;
  while (idx >= a.estart[s + 1]) ++s;
  int j = idx - a.estart[s];
  bias[idx] = (j < a.n[s]) ? rdf(a.src[s], j, fl) : 0.0f;
}

// ---------------- W2-fold precompute ----------------
// updW1Tf[l][n][k]: k<128 copy of updW1T; k>=128: (W2*U1b)^T = sum_j W2[k'][j]*U1b[j][n]
__global__ void fold_w2(const short* __restrict__ updW1T, const short* __restrict__ msgW2T,
                        short* __restrict__ updW1Tf) {
  int idx = blockIdx.x * 256 + threadIdx.x;  // 7*128*256
  int k = idx & 255; int n = (idx >> 8) & 127; int l = idx >> 15;
  if (k < 128) { updW1Tf[idx] = updW1T[idx]; return; }
  int kk = k - 128;
  const short* w2 = msgW2T + l * 128 * 128;                 // [j][kk] = W2[kk][j]
  const short* u1 = updW1T + l * 128 * 256 + n * 256 + 128; // [j]     = U1b[j][n]
  float s = 0.f;
  for (int j = 0; j < 128; ++j) s += bf2f(w2[j * 128 + kk]) * bf2f(u1[j]);
  updW1Tf[idx] = f2bf(s);
}

// b2U[l][n] = sum_j b2[l][j] * U1b[j][n]
__global__ void fold_b2(const float* __restrict__ msgB2f, const short* __restrict__ updW1T,
                        float* __restrict__ b2U) {
  int idx = blockIdx.x * 256 + threadIdx.x;  // 7*128
  if (idx >= 7 * 128) return;
  int n = idx & 127, l = idx >> 7;
  const short* u1 = updW1T + l * 128 * 256 + n * 256 + 128;
  const float* b2 = msgB2f + l * 128;
  float s = 0.f;
  for (int j = 0; j < 128; ++j) s += b2[j] * bf2f(u1[j]);
  b2U[idx] = s;
}

// ---------------- edge sort (counting sort by dst, hierarchical scan) ----------------

__global__ void hist_kernel(const int* __restrict__ eidx, const int* __restrict__ iflag,
                            int* __restrict__ counts, int E) {
  int e = blockIdx.x * 256 + threadIdx.x;
  if (e >= E) return;
  int fl = *iflag;
  int d = fl ? eidx[2 * (E + e)] : eidx[E + e];
  atomicAdd(&counts[d], 1);
}

__global__ void scan_bsum(const int* __restrict__ counts, int* __restrict__ bsums, int N) {
  int i = blockIdx.x * 256 + threadIdx.x;
  int v = (i < N) ? counts[i] : 0;
#pragma unroll
  for (int off = 1; off < 64; off <<= 1) v += __shfl_xor(v, off);
  __shared__ int ws4[4];
  if ((threadIdx.x & 63) == 0) ws4[threadIdx.x >> 6] = v;
  __syncthreads();
  if (threadIdx.x == 0) bsums[blockIdx.x] = ws4[0] + ws4[1] + ws4[2] + ws4[3];
}

// single block, in-place exclusive scan of up to 1024 block sums
__global__ void scan_top(int* __restrict__ bsums, int nb) {
  __shared__ int sh[1024];
  int t = threadIdx.x;
  int v = (t < nb) ? bsums[t] : 0;
  sh[t] = v;
  __syncthreads();
  for (int off = 1; off < 1024; off <<= 1) {
    int u = (t >= off) ? sh[t - off] : 0;
    __syncthreads();
    sh[t] += u;
    __syncthreads();
  }
  if (t < nb) bsums[t] = sh[t] - v;  // exclusive
}

__global__ void scan_final(const int* __restrict__ counts, const int* __restrict__ bsums,
                           int* __restrict__ row_start, int* __restrict__ cursor,
                           float* __restrict__ deg, int N, int E) {
  int i = blockIdx.x * 256 + threadIdx.x;
  int c = (i < N) ? counts[i] : 0;
  int lane = threadIdx.x & 63, w = threadIdx.x >> 6;
  int x = c;
#pragma unroll
  for (int off = 1; off < 64; off <<= 1) {
    int u = __shfl_up(x, off);
    if (lane >= off) x += u;
  }
  __shared__ int wsum[4];
  if (lane == 63) wsum[w] = x;
  __syncthreads();
  int wpre = 0;
#pragma unroll
  for (int k = 0; k < 4; ++k)
    if (k < w) wpre += wsum[k];
  int excl = bsums[blockIdx.x] + wpre + x - c;
  if (i < N) {
    row_start[i] = excl;
    cursor[i] = excl;
    deg[i] = (float)c;
  }
  if (i == N - 1) row_start[N] = E;
}

__global__ void scatter_kernel(const int* __restrict__ eidx, const int* __restrict__ iflag,
                               int* __restrict__ cursor, int* __restrict__ ssrc, int E) {
  int e = blockIdx.x * 256 + threadIdx.x;
  if (e >= E) return;
  int fl = *iflag;
  int d = fl ? eidx[2 * (E + e)] : eidx[E + e];
  int sv = fl ? eidx[2 * e] : eidx[e];
  int pos = atomicAdd(&cursor[d], 1);
  ssrc[pos] = sv;
}

// ---------------- P/Q GEMM: P = x@W1a + b1 (fp32), Q = x@W1b (bf16) ----------------

__global__ __launch_bounds__(256, 2)
void gemm_pq(const short* __restrict__ x, const short* __restrict__ W1T,
             const float* __restrict__ b1, float* __restrict__ P, short* __restrict__ Qs) {
  __shared__ __align__(16) char lds[65536];
  const int tid = threadIdx.x;
  const int w = tid >> 6, lane = tid & 63;
  const int quad = lane >> 4, l16 = lane & 15;
  const int R0 = blockIdx.x * 128;

#pragma unroll
  for (int c = 0; c < 16; ++c) {
    int slot = w * 16 + c;
    int mat = slot >> 5, id = slot & 31;
    int s = id >> 3, t = id & 7;
    int n = t * 16 + l16, k = s * 32 + quad * 8;
    gl_lds16(W1T + n * 256 + mat * 128 + k, lds + mat * 32768 + id * 1024 + lane * 16);
  }

  short8 afrag[4][2];
#pragma unroll
  for (int mt = 0; mt < 2; ++mt) {
    int m = R0 + w * 32 + mt * 16 + l16;
    const short* pr = x + (size_t)m * HH;
#pragma unroll
    for (int s = 0; s < 4; ++s) afrag[s][mt] = *(const short8*)(pr + s * 32 + quad * 8);
  }

  float b1f[8];
#pragma unroll
  for (int t = 0; t < 8; ++t) b1f[t] = b1[t * 16 + l16];

  __syncthreads();

  floatx4 zero4 = {0.f, 0.f, 0.f, 0.f};
  {
    floatx4 acc[2][8];
#pragma unroll
    for (int mt = 0; mt < 2; ++mt)
#pragma unroll
      for (int t = 0; t < 8; ++t) acc[mt][t] = zero4;
#pragma unroll
    for (int s = 0; s < 4; ++s) {
      short8 bfrag[8];
#pragma unroll
      for (int t = 0; t < 8; ++t)
        bfrag[t] = *(const short8*)(lds + (s * 8 + t) * 1024 + lane * 16);
#pragma unroll
      for (int mt = 0; mt < 2; ++mt)
#pragma unroll
        for (int t = 0; t < 8; ++t)
          acc[mt][t] = __builtin_amdgcn_mfma_f32_16x16x32_bf16(afrag[s][mt], bfrag[t], acc[mt][t], 0, 0, 0);
    }
#pragma unroll
    for (int mt = 0; mt < 2; ++mt)
#pragma unroll
      for (int nt = 0; nt < 8; ++nt) {
        int col = nt * 16 + l16;
#pragma unroll
        for (int r = 0; r < 4; ++r) {
          int row = R0 + w * 32 + mt * 16 + quad * 4 + r;
          P[(size_t)row * HH + col] = acc[mt][nt][r] + b1f[nt];
        }
      }
  }
  {
    floatx4 acc[2][8];
#pragma unroll
    for (int mt = 0; mt < 2; ++mt)
#pragma unroll
      for (int t = 0; t < 8; ++t) acc[mt][t] = zero4;
#pragma unroll
    for (int s = 0; s < 4; ++s) {
      short8 bfrag[8];
#pragma unroll
      for (int t = 0; t < 8; ++t)
        bfrag[t] = *(const short8*)(lds + 32768 + (s * 8 + t) * 1024 + lane * 16);
#pragma unroll
      for (int mt = 0; mt < 2; ++mt)
#pragma unroll
        for (int t = 0; t < 8; ++t)
          acc[mt][t] = __builtin_amdgcn_mfma_f32_16x16x32_bf16(afrag[s][mt], bfrag[t], acc[mt][t], 0, 0, 0);
    }
#pragma unroll
    for (int mt = 0; mt < 2; ++mt)
#pragma unroll
      for (int nt = 0; nt < 8; ++nt) {
        int col = nt * 16 + l16;
#pragma unroll
        for (int r = 0; r < 4; ++r) {
          int row = R0 + w * 32 + mt * 16 + quad * 4 + r;
          Qs[(size_t)row * HH + col] = f2bf(acc[mt][nt][r]);
        }
      }
  }
}

// ---------------- edge aggregation: Hagg[d] = sum relu(P[d] + Q[src]) ----------------

__global__ __launch_bounds__(256)
void edge_agg(const float* __restrict__ P, const uint32_t* __restrict__ Qp,
              const int* __restrict__ ssrc, const int* __restrict__ row_start,
              uint32_t* __restrict__ Hagg, int Ntot) {
  int w = threadIdx.x >> 6, lane = threadIdx.x & 63;
  int d = blockIdx.x * 4 + w;
  if (d >= Ntot) return;
  float px = P[(size_t)d * HH + 2 * lane];
  float py = P[(size_t)d * HH + 2 * lane + 1];
  int s0 = row_start[d], s1 = row_start[d + 1];
  float ax = 0.f, ay = 0.f;
  int e = s0;
  for (; e + 4 <= s1; e += 4) {
    int i0 = ssrc[e], i1 = ssrc[e + 1], i2 = ssrc[e + 2], i3 = ssrc[e + 3];
    uint32_t q0 = Qp[(size_t)i0 * 64 + lane];
    uint32_t q1 = Qp[(size_t)i1 * 64 + lane];
    uint32_t q2 = Qp[(size_t)i2 * 64 + lane];
    uint32_t q3 = Qp[(size_t)i3 * 64 + lane];
    float hx, hy;
    hx = px + bf2f((short)(q0 & 0xffff)); hy = py + bf2f((short)(q0 >> 16));
    ax += hx > 0.f ? hx : 0.f; ay += hy > 0.f ? hy : 0.f;
    hx = px + bf2f((short)(q1 & 0xffff)); hy = py + bf2f((short)(q1 >> 16));
    ax += hx > 0.f ? hx : 0.f; ay += hy > 0.f ? hy : 0.f;
    hx = px + bf2f((short)(q2 & 0xffff)); hy = py + bf2f((short)(q2 >> 16));
    ax += hx > 0.f ? hx : 0.f; ay += hy > 0.f ? hy : 0.f;
    hx = px + bf2f((short)(q3 & 0xffff)); hy = py + bf2f((short)(q3 >> 16));
    ax += hx > 0.f ? hx : 0.f; ay += hy > 0.f ? hy : 0.f;
  }
  for (; e < s1; ++e) {
    int i0 = ssrc[e];
    uint32_t q0 = Qp[(size_t)i0 * 64 + lane];
    float hx = px + bf2f((short)(q0 & 0xffff));
    float hy = py + bf2f((short)(q0 >> 16));
    ax += hx > 0.f ? hx : 0.f;
    ay += hy > 0.f ? hy : 0.f;
  }
  uint32_t packed = (uint32_t)(uint16_t)f2bf(ax) | ((uint32_t)(uint16_t)f2bf(ay) << 16);
  Hagg[(size_t)d * 64 + lane] = packed;
}

// ---------------- fused 2-layer MLP kernel (MODE: 0=EMBED 2=UPD 3=HEAD) ----------------
// MODE 2: A = cat(x, Hagg), W1 = cat(U1a, W2*U1b); hidden bias gets + deg*b2U.

template <int MODE>
__global__ __launch_bounds__(256, 2)
void mlp2_kernel(const short* __restrict__ Asrc, const short* __restrict__ Asrc2,
                 const short* __restrict__ W1T, const float* __restrict__ b1,
                 const short* __restrict__ W2T, const float* __restrict__ b2,
                 short* __restrict__ outbf, float* __restrict__ outf,
                 const float* __restrict__ deg, const float* __restrict__ b2Uv) {
  constexpr int K1 = (MODE == 0) ? 64 : (MODE == 3) ? 128 : 256;
  constexpr int NS = K1 / 32;
  constexpr int N2T = (MODE == 3) ? 2 : 8;

  __shared__ __align__(16) char lds[65536];

  const int tid = threadIdx.x;
  const int w = tid >> 6, lane = tid & 63;
  const int quad = lane >> 4, l16 = lane & 15;
  const int R0 = blockIdx.x * 128;

#pragma unroll
  for (int c = 0; c < NS * 2; ++c) {
    int slot = w * (NS * 2) + c;
    int s = slot >> 3, t = slot & 7;
    int n = t * 16 + l16, k = s * 32 + quad * 8;
    gl_lds16(W1T + n * K1 + k, lds + slot * 1024 + lane * 16);
  }

  short8 afrag[NS][2];
  if constexpr (MODE == 2) {
#pragma unroll
    for (int mt = 0; mt < 2; ++mt) {
      int m = R0 + w * 32 + mt * 16 + l16;
      const short* pr = Asrc + (size_t)m * HH;
      const short* ar = Asrc2 + (size_t)m * HH;
#pragma unroll
      for (int s = 0; s < 4; ++s) {
        afrag[s][mt] = *(const short8*)(pr + s * 32 + quad * 8);
        afrag[s + 4][mt] = *(const short8*)(ar + s * 32 + quad * 8);
      }
    }
  } else {
    constexpr int ST = (MODE == 0) ? 64 : HH;
#pragma unroll
    for (int mt = 0; mt < 2; ++mt) {
      int m = R0 + w * 32 + mt * 16 + l16;
      const short* pr = Asrc + (size_t)m * ST;
#pragma unroll
      for (int s = 0; s < NS; ++s) afrag[s][mt] = *(const short8*)(pr + s * 32 + quad * 8);
    }
  }

  float b1f[8], b2f[N2T], b2u[8];
  float dvals[2][4];
#pragma unroll
  for (int t = 0; t < 8; ++t) b1f[t] = b1[t * 16 + l16];
#pragma unroll
  for (int t = 0; t < N2T; ++t) b2f[t] = b2[t * 16 + l16];
  if constexpr (MODE == 2) {
#pragma unroll
    for (int t = 0; t < 8; ++t) b2u[t] = b2Uv[t * 16 + l16];
#pragma unroll
    for (int mt = 0; mt < 2; ++mt)
#pragma unroll
      for (int r = 0; r < 4; ++r)
        dvals[mt][r] = deg[R0 + w * 32 + mt * 16 + quad * 4 + r];
  }

  __syncthreads();

  floatx4 acc[2][8];
  floatx4 zero4 = {0.f, 0.f, 0.f, 0.f};
#pragma unroll
  for (int mt = 0; mt < 2; ++mt)
#pragma unroll
    for (int t = 0; t < 8; ++t) acc[mt][t] = zero4;

#pragma unroll
  for (int s = 0; s < NS; ++s) {
    short8 bfrag[8];
#pragma unroll
    for (int t = 0; t < 8; ++t)
      bfrag[t] = *(const short8*)(lds + (s * 8 + t) * 1024 + lane * 16);
#pragma unroll
    for (int mt = 0; mt < 2; ++mt)
#pragma unroll
      for (int t = 0; t < 8; ++t)
        acc[mt][t] = __builtin_amdgcn_mfma_f32_16x16x32_bf16(afrag[s][mt], bfrag[t], acc[mt][t], 0, 0, 0);
  }

  __syncthreads();

#pragma unroll
  for (int c = 0; c < N2T; ++c) {
    int n = c * 16 + l16, k = w * 32 + quad * 8;
    gl_lds16(W2T + n * HH + k, lds + 32768 + (w * N2T + c) * 1024 + lane * 16);
  }

  const int mtgb = w * 2;
#pragma unroll
  for (int mt = 0; mt < 2; ++mt) {
#pragma unroll
    for (int nt = 0; nt < 8; ++nt) {
      floatx4 v = acc[mt][nt];
      int s2 = nt >> 1;
      int lpb = 16 * ((nt & 1) * 2 + (l16 >> 3));
      int joff = 2 * (l16 & 7);
      char* base = lds + (size_t)(s2 * 8 + mtgb + mt) * 1024 + joff;
#pragma unroll
      for (int r = 0; r < 4; ++r) {
        float h = v[r] + b1f[nt];
        if constexpr (MODE == 2) h += dvals[mt][r] * b2u[nt];
        h = h > 0.f ? h : 0.f;
        *(short*)(base + (quad * 4 + r + lpb) * 16) = f2bf(h);
      }
    }
  }

  __syncthreads();

  floatx4 acc2[2][N2T];
#pragma unroll
  for (int mt = 0; mt < 2; ++mt)
#pragma unroll
    for (int t = 0; t < N2T; ++t) acc2[mt][t] = zero4;

#pragma unroll
  for (int s2 = 0; s2 < 4; ++s2) {
    short8 af[2];
#pragma unroll
    for (int mt = 0; mt < 2; ++mt)
      af[mt] = *(const short8*)(lds + (s2 * 8 + mtgb + mt) * 1024 + lane * 16);
    short8 bfr[N2T];
#pragma unroll
    for (int t = 0; t < N2T; ++t)
      bfr[t] = *(const short8*)(lds + 32768 + (s2 * N2T + t) * 1024 + lane * 16);
#pragma unroll
    for (int mt = 0; mt < 2; ++mt)
#pragma unroll
      for (int t = 0; t < N2T; ++t)
        acc2[mt][t] = __builtin_amdgcn_mfma_f32_16x16x32_bf16(af[mt], bfr[t], acc2[mt][t], 0, 0, 0);
  }

  if constexpr (MODE == 3) {
#pragma unroll
    for (int mt = 0; mt < 2; ++mt)
#pragma unroll
      for (int nt = 0; nt < N2T; ++nt) {
        int col = nt * 16 + l16;
#pragma unroll
        for (int r = 0; r < 4; ++r) {
          int row = R0 + w * 32 + mt * 16 + quad * 4 + r;
          outf[(size_t)row * 32 + col] = acc2[mt][nt][r] + b2f[nt];
        }
      }
  } else {
#pragma unroll
    for (int mt = 0; mt < 2; ++mt)
#pragma unroll
      for (int nt = 0; nt < 8; ++nt) {
        int col = nt * 16 + l16;
#pragma unroll
        for (int r = 0; r < 4; ++r) {
          int row = R0 + w * 32 + mt * 16 + quad * 4 + r;
          outbf[(size_t)row * HH + col] = f2bf(acc2[mt][nt][r] + b2f[nt]);
        }
      }
  }
}

// ---------------- loss ----------------

__global__ void loss_kernel(const float* __restrict__ out32, const void* __restrict__ loc,
                            const void* __restrict__ yv, const int* __restrict__ dflag,
                            float* __restrict__ out, float* __restrict__ acc, int NB) {
  int fl = *dflag;
  int i = blockIdx.x * 256 + threadIdx.x;
  const float* o = out32 + (size_t)i * 32;
  float dsum = 0.f, fde = 0.f;
#pragma unroll
  for (int f = 0; f < 10; ++f) {
    float dx = o[f * 3 + 0] + rdf(loc, i * 30 + f * 3 + 0, fl) - rdf(yv, i * 30 + f * 3 + 0, fl);
    float dy = o[f * 3 + 1] + rdf(loc, i * 30 + f * 3 + 1, fl) - rdf(yv, i * 30 + f * 3 + 1, fl);
    float dz = o[f * 3 + 2] + rdf(loc, i * 30 + f * 3 + 2, fl) - rdf(yv, i * 30 + f * 3 + 2, fl);
    float d = sqrtf(dx * dx + dy * dy + dz * dz);
    dsum += d;
    if (f == 9) fde = d;
  }
#pragma unroll
  for (int m = 1; m < 16; m <<= 1) {
    dsum += __shfl_xor(dsum, m);
    fde += __shfl_xor(fde, m);
  }
  if ((threadIdx.x & 15) == 0) {
    int b = i >> 4;
    out[1 + b] = dsum / 160.0f;
    out[1 + NB + b] = fde / 16.0f;
    unsafeAtomicAdd(acc, dsum);
  }
}

__global__ void final_kernel(const float* __restrict__ acc, float* __restrict__ out, float inv) {
  if (threadIdx.x == 0) out[0] = *acc * inv;
}

// ---------------- host ----------------

extern "C" void kernel_launch(void* const* d_in, const int* in_sizes, int n_in,
                              void* d_out, int out_size, void* d_ws, size_t ws_size,
                              hipStream_t stream) {
  const void* loc = d_in[0];
  const void* vel = d_in[1];
  const void* yv = d_in[2];
  const int* eidx = (const int*)d_in[3];

  const int N = in_sizes[0] / 30;  // 32768
  const int E = in_sizes[3] / 2;   // 524288
  const int L = 7;
  const int NB = N / 16;

  const size_t MB = 1024 * 1024;
  char* ws = (char*)d_ws;
  short* x = (short*)ws;                     // N*128 bf16   [0,8)MB
  float* P = (float*)(ws + 8 * MB);          // N*128 f32    [8,24)MB
  short* in64 = (short*)(ws + 8 * MB);       // overlays P head
  short* Qs = (short*)(ws + 24 * MB);        // N*128 bf16   [24,32)MB
  short* Hagg = (short*)(ws + 32 * MB);      // N*128 bf16   [32,40)MB
  float* out32 = (float*)(ws + 32 * MB);     // overlays Hagg (post-layers)
  short* updW1Tf = (short*)(ws + 40 * MB);   // 7*128*256 bf16 (448KB)
  int* bsums = (int*)(ws + 41 * MB);         // 1024 ints
  short* wbase = (short*)(ws + 48 * MB);     // 733184 shorts (~1.4MB)
  const unsigned long long OFF_EMBW1 = 0;
  const unsigned long long OFF_EMBW2 = 8192;
  const unsigned long long OFF_HEADW1 = 24576;
  const unsigned long long OFF_HEADW2 = 40960;
  const unsigned long long OFF_MSGW1 = 45056;
  const unsigned long long OFF_MSGW2 = 274432;
  const unsigned long long OFF_UPDW1 = 389120;
  const unsigned long long OFF_UPDW2 = 618496;
  short* embW1T = wbase + OFF_EMBW1;
  short* embW2T = wbase + OFF_EMBW2;
  short* headW1T = wbase + OFF_HEADW1;
  short* headW2T = wbase + OFF_HEADW2;
  short* msgW1T = wbase + OFF_MSGW1;
  short* msgW2T = wbase + OFF_MSGW2;
  short* updW1T = wbase + OFF_UPDW1;
  short* updW2T = wbase + OFF_UPDW2;
  float* bias = (float*)(ws + 49 * MB + 512 * 1024);
  float* embB1f = bias;
  float* embB2f = bias + 128;
  float* msgB1f = bias + 256;
  float* msgB2f = bias + 1152;
  float* updB1f = bias + 2048;
  float* updB2f = bias + 2944;
  float* headB1f = bias + 3840;
  float* headB2f = bias + 3968;
  float* b2U = bias + 4096;                            // 7*128 fp32
  int* counts = (int*)(ws + 49 * MB + 768 * 1024);     // N ints
  int* row_start = (int*)(ws + 50 * MB);               // N+1 ints
  int* cursor = (int*)(ws + 50 * MB + 256 * 1024);     // N ints
  float* deg = (float*)(ws + 50 * MB + 512 * 1024);    // N floats
  int* iflag = (int*)(ws + 50 * MB + 768 * 1024);
  int* dflag = iflag + 16;
  float* accp = (float*)(iflag + 32);
  int* ssrc = (int*)(ws + 51 * MB);                    // E ints [51,53)MB

  detect_idx<<<1, 256, 0, stream>>>(eidx, iflag);
  detect_dtype<<<1, 256, 0, stream>>>((const uint32_t*)loc, dflag);

  // edge sort by dst (hierarchical scan)
  const int NBLK = (N + 255) / 256;  // 128
  hipMemsetAsync(counts, 0, (size_t)N * 4, stream);
  hist_kernel<<<(E + 255) / 256, 256, 0, stream>>>(eidx, iflag, counts, E);
  scan_bsum<<<NBLK, 256, 0, stream>>>(counts, bsums, N);
  scan_top<<<1, 1024, 0, stream>>>(bsums, NBLK);
  scan_final<<<NBLK, 256, 0, stream>>>(counts, bsums, row_start, cursor, deg, N, E);
  scatter_kernel<<<(E + 255) / 256, 256, 0, stream>>>(eidx, iflag, cursor, ssrc, E);

  pad_input<<<(N * 64) / 256, 256, 0, stream>>>(loc, vel, in64, dflag);

  // merged weight transpose (8 segments)
  {
    WPrep a;
    const void* srcs[8] = {d_in[5], d_in[7], d_in[17], d_in[19],
                           d_in[9], d_in[11], d_in[13], d_in[15]};
    unsigned long long offs[8] = {OFF_EMBW1, OFF_EMBW2, OFF_HEADW1, OFF_HEADW2,
                                  OFF_MSGW1, OFF_MSGW2, OFF_UPDW1, OFF_UPDW2};
    int Ls[8] = {1, 1, 1, 1, 7, 7, 7, 7};
    int Ks[8] = {60, 128, 128, 128, 256, 128, 256, 128};
    int Ns[8] = {128, 128, 128, 30, 128, 128, 128, 128};
    int Kps[8] = {64, 128, 128, 128, 256, 128, 256, 128};
    int Nps[8] = {128, 128, 128, 32, 128, 128, 128, 128};
    int cum = 0;
    for (int s = 0; s < 8; ++s) {
      a.src[s] = srcs[s]; a.dstoff[s] = offs[s];
      a.L[s] = Ls[s]; a.K[s] = Ks[s]; a.Nn[s] = Ns[s]; a.Kp[s] = Kps[s]; a.Np[s] = Nps[s];
      a.bstart[s] = cum;
      cum += (Ls[s] * Nps[s] * Kps[s] + 255) / 256;
    }
    a.bstart[8] = cum;
    prep_w<<<cum, 256, 0, stream>>>(a, wbase, dflag);
  }

  // merged bias conversion (8 segments)
  {
    BPrep a;
    const void* srcs[8] = {d_in[6], d_in[8], d_in[10], d_in[12],
                           d_in[14], d_in[16], d_in[18], d_in[20]};
    int ns[8] = {128, 128, 896, 896, 896, 896, 128, 30};
    int es[9] = {0, 128, 256, 1152, 2048, 2944, 3840, 3968, 4000};
    for (int s = 0; s < 8; ++s) { a.src[s] = srcs[s]; a.n[s] = ns[s]; a.estart[s] = es[s]; }
    a.estart[8] = es[8];
    prep_b<<<16, 256, 0, stream>>>(a, bias, dflag);
  }

  // fold W2 into upd GEMM1 (after prep_w / prep_b)
  fold_w2<<<7 * 128, 256, 0, stream>>>(updW1T, msgW2T, updW1Tf);
  fold_b2<<<4, 256, 0, stream>>>(msgB2f, updW1T, b2U);

  mlp2_kernel<0><<<N / 128, 256, 0, stream>>>(in64, nullptr,
      embW1T, embB1f, embW2T, embB2f, x, nullptr, nullptr, nullptr);

  for (int l = 0; l < L; ++l) {
    gemm_pq<<<N / 128, 256, 0, stream>>>(x, msgW1T + l * 128 * 256, msgB1f + l * 128, P, Qs);
    edge_agg<<<(N + 3) / 4, 256, 0, stream>>>(P, (const uint32_t*)Qs, ssrc, row_start,
                                              (uint32_t*)Hagg, N);
    mlp2_kernel<2><<<N / 128, 256, 0, stream>>>(x, Hagg,
        updW1Tf + l * 128 * 256, updB1f + l * 128, updW2T + l * 128 * 128, updB2f + l * 128,
        x, nullptr, deg, b2U + l * 128);
  }

  mlp2_kernel<3><<<N / 128, 256, 0, stream>>>(x, nullptr,
      headW1T, headB1f, headW2T, headB2f, nullptr, out32, nullptr, nullptr);

  hipMemsetAsync(accp, 0, 4, stream);
  loss_kernel<<<N / 256, 256, 0, stream>>>(out32, loc, yv, dflag, (float*)d_out, accp, NB);
  final_kernel<<<1, 64, 0, stream>>>(accp, (float*)d_out, 1.0f / 327680.0f);
}

// Round 5
// 532.981 us; speedup vs baseline: 3.6634x; 1.0755x over previous
//
#include <hip/hip_runtime.h>
#include <hip/hip_bf16.h>
#include <stdint.h>

#define HH 128

typedef __attribute__((ext_vector_type(8))) short short8;
typedef __attribute__((ext_vector_type(4))) float floatx4;

typedef __attribute__((address_space(3))) uint32_t lds_u32_t;
typedef const __attribute__((address_space(1))) uint32_t gbl_u32_t;

__device__ __forceinline__ void gl_lds16(const void* g, void* l) {
  __builtin_amdgcn_global_load_lds((gbl_u32_t*)g, (lds_u32_t*)l, 16, 0, 0);
}

__device__ __forceinline__ float bf2f(short v) {
  union { uint32_t u; float f; } x; x.u = ((uint32_t)(uint16_t)v) << 16; return x.f;
}
__device__ __forceinline__ short f2bf(float f) {
  union { float f; uint32_t u; } x; x.f = f;
  uint32_t r = x.u + 0x7fffu + ((x.u >> 16) & 1u);
  return (short)(r >> 16);
}
__device__ __forceinline__ float rdf(const void* p, int i, int fl) {
  return fl ? bf2f(((const short*)p)[i]) : ((const float*)p)[i];
}

// ---------------- probe + zero kernel ----------------
// grid (N+255)/256: zeroes counts; block 0 also probes idx layout / dtype, zeroes accp

__global__ void detect_zero(const int* __restrict__ eidx, int* iflag, int* dflag,
                            int* __restrict__ counts, float* accp,
                            const uint32_t* __restrict__ loc, int N) {
  int g = blockIdx.x * 256 + threadIdx.x;
  if (g < N) counts[g] = 0;
  if (blockIdx.x == 0) {
    __shared__ int nz, cnt;
    if (threadIdx.x == 0) { nz = 0; cnt = 0; *accp = 0.f; }
    __syncthreads();
    int any = 0;
    for (int i = threadIdx.x; i < 1024; i += 256) any |= (eidx[2 * i + 1] != 0);
    if (any) atomicOr(&nz, 1);
    uint32_t u = loc[threadIdx.x];
    int e = (u >> 7) & 0xFF;
    if (e >= 100 && e <= 140) atomicAdd(&cnt, 1);
    __syncthreads();
    if (threadIdx.x == 0) {
      *iflag = (nz == 0) ? 1 : 0;   // 1 => int64 layout
      *dflag = (cnt >= 192) ? 1 : 0; // 1 => bf16 tensors
    }
  }
}

// ---------------- prep kernels ----------------

__global__ void pad_input(const void* __restrict__ loc, const void* __restrict__ vel,
                          short* __restrict__ dst, const int* __restrict__ dflag) {
  int fl = *dflag;
  int idx = blockIdx.x * 256 + threadIdx.x;
  int j = idx & 63, i = idx >> 6;
  short v = 0;
  if (j < 60) {
    int f = j / 6, c = j % 6;
    float x = (c < 3) ? rdf(loc, (i * 10 + f) * 3 + c, fl)
                      : rdf(vel, (i * 10 + f) * 3 + (c - 3), fl);
    v = f2bf(x);
  }
  dst[idx] = v;
}

struct WPrep {
  const void* src[8];
  unsigned long long dstoff[8];
  int L[8], K[8], Nn[8], Kp[8], Np[8];
  int bstart[9];
};

__global__ void prep_w(WPrep a, short* __restrict__ wbase, const int* __restrict__ dflag) {
  int fl = *dflag;
  int b = blockIdx.x;
  int s = 0;
  while (b >= a.bstart[s + 1]) ++s;
  int idx = (b - a.bstart[s]) * 256 + threadIdx.x;
  int Kp = a.Kp[s], Np = a.Np[s], K = a.K[s], Nn = a.Nn[s];
  int tot = a.L[s] * Np * Kp;
  if (idx >= tot) return;
  int k = idx % Kp; int rest = idx / Kp; int n = rest % Np; int l = rest / Np;
  short v = 0;
  if (k < K && n < Nn) v = f2bf(rdf(a.src[s], (l * K + k) * Nn + n, fl));
  wbase[a.dstoff[s] + idx] = v;
}

struct BPrep {
  const void* src[8];
  int n[8];
  int estart[9];
};

__global__ void prep_b(BPrep a, float* __restrict__ bias, const int* __restrict__ dflag) {
  int fl = *dflag;
  int idx = blockIdx.x * 256 + threadIdx.x;
  if (idx >= a.estart[8]) return;
  int s = 0;
  while (idx >= a.estart[s + 1]) ++s;
  int j = idx - a.estart[s];
  bias[idx] = (j < a.n[s]) ? rdf(a.src[s], j, fl) : 0.0f;
}

// ---------------- W2-fold precompute (w2 + b2 merged) ----------------

__global__ void fold_kernel(const short* __restrict__ updW1T, const short* __restrict__ msgW2T,
                            short* __restrict__ updW1Tf, const float* __restrict__ msgB2f,
                            float* __restrict__ b2U) {
  if (blockIdx.x < 896) {
    int idx = blockIdx.x * 256 + threadIdx.x;  // 7*128*256
    int k = idx & 255; int n = (idx >> 8) & 127; int l = idx >> 15;
    if (k < 128) { updW1Tf[idx] = updW1T[idx]; return; }
    int kk = k - 128;
    const short* w2 = msgW2T + l * 128 * 128;
    const short* u1 = updW1T + l * 128 * 256 + n * 256 + 128;
    float s = 0.f;
    for (int j = 0; j < 128; ++j) s += bf2f(w2[j * 128 + kk]) * bf2f(u1[j]);
    updW1Tf[idx] = f2bf(s);
  } else {
    int idx = (blockIdx.x - 896) * 256 + threadIdx.x;  // 7*128
    if (idx >= 7 * 128) return;
    int n = idx & 127, l = idx >> 7;
    const short* u1 = updW1T + l * 128 * 256 + n * 256 + 128;
    const float* b2 = msgB2f + l * 128;
    float s = 0.f;
    for (int j = 0; j < 128; ++j) s += b2[j] * bf2f(u1[j]);
    b2U[idx] = s;
  }
}

// ---------------- edge sort (counting sort by dst) ----------------

__global__ void hist_kernel(const int* __restrict__ eidx, const int* __restrict__ iflag,
                            int* __restrict__ counts, int E) {
  int e = blockIdx.x * 256 + threadIdx.x;
  if (e >= E) return;
  int fl = *iflag;
  int d = fl ? eidx[2 * (E + e)] : eidx[E + e];
  atomicAdd(&counts[d], 1);
}

__global__ void scan_bsum(const int* __restrict__ counts, int* __restrict__ bsums, int N) {
  int i = blockIdx.x * 256 + threadIdx.x;
  int v = (i < N) ? counts[i] : 0;
#pragma unroll
  for (int off = 1; off < 64; off <<= 1) v += __shfl_xor(v, off);
  __shared__ int ws4[4];
  if ((threadIdx.x & 63) == 0) ws4[threadIdx.x >> 6] = v;
  __syncthreads();
  if (threadIdx.x == 0) bsums[blockIdx.x] = ws4[0] + ws4[1] + ws4[2] + ws4[3];
}

// per-block: reduce bsums[0..blockIdx.x) internally, then local scan (assumes grid <= 128)
__global__ void scan_final(const int* __restrict__ counts, const int* __restrict__ bsums,
                           int* __restrict__ row_start, int* __restrict__ cursor,
                           float* __restrict__ deg, int N, int E) {
  int t = threadIdx.x;
  __shared__ int shb[2];
  __shared__ int wsum[4];
  int v = (t < 128 && t < (int)blockIdx.x) ? bsums[t] : 0;
#pragma unroll
  for (int off = 1; off < 64; off <<= 1) v += __shfl_xor(v, off);
  if (t == 0) shb[0] = v;
  if (t == 64) shb[1] = v;
  int i = blockIdx.x * 256 + t;
  int c = (i < N) ? counts[i] : 0;
  int lane = t & 63, w = t >> 6;
  int x = c;
#pragma unroll
  for (int off = 1; off < 64; off <<= 1) {
    int u = __shfl_up(x, off);
    if (lane >= off) x += u;
  }
  if (lane == 63) wsum[w] = x;
  __syncthreads();
  int wpre = 0;
#pragma unroll
  for (int k = 0; k < 4; ++k)
    if (k < w) wpre += wsum[k];
  int excl = shb[0] + shb[1] + wpre + x - c;
  if (i < N) {
    row_start[i] = excl;
    cursor[i] = excl;
    deg[i] = (float)c;
  }
  if (i == N - 1) row_start[N] = E;
}

__global__ void scatter_kernel(const int* __restrict__ eidx, const int* __restrict__ iflag,
                               int* __restrict__ cursor, int* __restrict__ ssrc, int E) {
  int e = blockIdx.x * 256 + threadIdx.x;
  if (e >= E) return;
  int fl = *iflag;
  int d = fl ? eidx[2 * (E + e)] : eidx[E + e];
  int sv = fl ? eidx[2 * e] : eidx[e];
  int pos = atomicAdd(&cursor[d], 1);
  ssrc[pos] = sv;
}

// ---------------- edge aggregation: Hagg[d] = sum relu(P[d] + Q[src]) ----------------

__global__ __launch_bounds__(256)
void edge_agg(const float* __restrict__ P, const uint32_t* __restrict__ Qp,
              const int* __restrict__ ssrc, const int* __restrict__ row_start,
              uint32_t* __restrict__ Hagg, int Ntot) {
  int w = threadIdx.x >> 6, lane = threadIdx.x & 63;
  int d = blockIdx.x * 4 + w;
  if (d >= Ntot) return;
  float px = P[(size_t)d * HH + 2 * lane];
  float py = P[(size_t)d * HH + 2 * lane + 1];
  int s0 = row_start[d], s1 = row_start[d + 1];
  float ax = 0.f, ay = 0.f;
  int e = s0;
  for (; e + 4 <= s1; e += 4) {
    int i0 = ssrc[e], i1 = ssrc[e + 1], i2 = ssrc[e + 2], i3 = ssrc[e + 3];
    uint32_t q0 = Qp[(size_t)i0 * 64 + lane];
    uint32_t q1 = Qp[(size_t)i1 * 64 + lane];
    uint32_t q2 = Qp[(size_t)i2 * 64 + lane];
    uint32_t q3 = Qp[(size_t)i3 * 64 + lane];
    float hx, hy;
    hx = px + bf2f((short)(q0 & 0xffff)); hy = py + bf2f((short)(q0 >> 16));
    ax += hx > 0.f ? hx : 0.f; ay += hy > 0.f ? hy : 0.f;
    hx = px + bf2f((short)(q1 & 0xffff)); hy = py + bf2f((short)(q1 >> 16));
    ax += hx > 0.f ? hx : 0.f; ay += hy > 0.f ? hy : 0.f;
    hx = px + bf2f((short)(q2 & 0xffff)); hy = py + bf2f((short)(q2 >> 16));
    ax += hx > 0.f ? hx : 0.f; ay += hy > 0.f ? hy : 0.f;
    hx = px + bf2f((short)(q3 & 0xffff)); hy = py + bf2f((short)(q3 >> 16));
    ax += hx > 0.f ? hx : 0.f; ay += hy > 0.f ? hy : 0.f;
  }
  for (; e < s1; ++e) {
    int i0 = ssrc[e];
    uint32_t q0 = Qp[(size_t)i0 * 64 + lane];
    float hx = px + bf2f((short)(q0 & 0xffff));
    float hy = py + bf2f((short)(q0 >> 16));
    ax += hx > 0.f ? hx : 0.f;
    ay += hy > 0.f ? hy : 0.f;
  }
  uint32_t packed = (uint32_t)(uint16_t)f2bf(ax) | ((uint32_t)(uint16_t)f2bf(ay) << 16);
  Hagg[(size_t)d * 64 + lane] = packed;
}

// ---------------- fused MLP helpers ----------------

// write a per-wave 32x128 C-layout tile into K-major A-slots at lds[0:32768)
__device__ __forceinline__ void write_aslots(char* lds, const floatx4 v2[2][8],
                                             int w, int quad, int l16) {
  const int mtgb = w * 2;
#pragma unroll
  for (int mt = 0; mt < 2; ++mt)
#pragma unroll
    for (int nt = 0; nt < 8; ++nt) {
      floatx4 v = v2[mt][nt];
      int s2 = nt >> 1;
      int lpb = 16 * ((nt & 1) * 2 + (l16 >> 3));
      int joff = 2 * (l16 & 7);
      char* base = lds + (size_t)(s2 * 8 + mtgb + mt) * 1024 + joff;
#pragma unroll
      for (int r = 0; r < 4; ++r)
        *(short*)(base + (quad * 4 + r + lpb) * 16) = f2bf(v[r]);
    }
}

// GEMM with A from lds[0:32768) A-slots and B from lds[32768+ (s2*NT+t)*1024)
template <int NT>
__device__ __forceinline__ void gemm_lds(const char* lds, int mtgb, floatx4 acc[2][NT], int lane) {
#pragma unroll
  for (int s2 = 0; s2 < 4; ++s2) {
    short8 af[2];
#pragma unroll
    for (int mt = 0; mt < 2; ++mt)
      af[mt] = *(const short8*)(lds + (s2 * 8 + mtgb + mt) * 1024 + lane * 16);
    short8 bfr[NT];
#pragma unroll
    for (int t = 0; t < NT; ++t)
      bfr[t] = *(const short8*)(lds + 32768 + (s2 * NT + t) * 1024 + lane * 16);
#pragma unroll
    for (int mt = 0; mt < 2; ++mt)
#pragma unroll
      for (int t = 0; t < NT; ++t)
        acc[mt][t] = __builtin_amdgcn_mfma_f32_16x16x32_bf16(af[mt], bfr[t], acc[mt][t], 0, 0, 0);
  }
}

// ---------------- fused MLP kernel ----------------
// MODE 0: embed (K1=64) -> x, then P/Q for layer 0
// MODE 2: upd (K1=256, W2-folded) -> x, then P/Q for next layer
// MODE 3: upd (layer 6) -> head MLP -> out32 (no x write, no P/Q)

template <int MODE>
__global__ __launch_bounds__(256, 2)
void mlp_fused(const short* __restrict__ Asrc, const short* __restrict__ Asrc2,
               const short* __restrict__ W1T, const float* __restrict__ b1,
               const short* __restrict__ W2T, const float* __restrict__ b2,
               const float* __restrict__ deg, const float* __restrict__ b2Uv,
               const short* __restrict__ pqW1, const float* __restrict__ pqB1,
               const short* __restrict__ pq2W, const float* __restrict__ pq2B,
               short* __restrict__ xout, float* __restrict__ Pout,
               short* __restrict__ Qout, float* __restrict__ out32) {
  constexpr int K1 = (MODE == 0) ? 64 : 256;
  constexpr int NS = K1 / 32;
  constexpr int PQS = (MODE == 3) ? 128 : 256;

  __shared__ __align__(16) char lds[65536];

  const int tid = threadIdx.x;
  const int w = tid >> 6, lane = tid & 63;
  const int quad = lane >> 4, l16 = lane & 15;
  const int R0 = blockIdx.x * 128;
  const int mtgb = w * 2;

  // stage W1T B-fragments
#pragma unroll
  for (int c = 0; c < NS * 2; ++c) {
    int slot = w * (NS * 2) + c;
    int s = slot >> 3, t = slot & 7;
    int n = t * 16 + l16, k = s * 32 + quad * 8;
    gl_lds16(W1T + n * K1 + k, lds + slot * 1024 + lane * 16);
  }

  // A fragments
  short8 afrag[NS][2];
  if constexpr (MODE == 0) {
#pragma unroll
    for (int mt = 0; mt < 2; ++mt) {
      int m = R0 + w * 32 + mt * 16 + l16;
      const short* pr = Asrc + (size_t)m * 64;
#pragma unroll
      for (int s = 0; s < NS; ++s) afrag[s][mt] = *(const short8*)(pr + s * 32 + quad * 8);
    }
  } else {
#pragma unroll
    for (int mt = 0; mt < 2; ++mt) {
      int m = R0 + w * 32 + mt * 16 + l16;
      const short* pr = Asrc + (size_t)m * HH;
      const short* ar = Asrc2 + (size_t)m * HH;
#pragma unroll
      for (int s = 0; s < 4; ++s) {
        afrag[s][mt] = *(const short8*)(pr + s * 32 + quad * 8);
        afrag[s + 4][mt] = *(const short8*)(ar + s * 32 + quad * 8);
      }
    }
  }

  float b1f[8], b2f[8], pb1[8], b2u[8];
  float dvals[2][4];
#pragma unroll
  for (int t = 0; t < 8; ++t) b1f[t] = b1[t * 16 + l16];
#pragma unroll
  for (int t = 0; t < 8; ++t) b2f[t] = b2[t * 16 + l16];
#pragma unroll
  for (int t = 0; t < 8; ++t) pb1[t] = pqB1[t * 16 + l16];
  if constexpr (MODE != 0) {
#pragma unroll
    for (int t = 0; t < 8; ++t) b2u[t] = b2Uv[t * 16 + l16];
#pragma unroll
    for (int mt = 0; mt < 2; ++mt)
#pragma unroll
      for (int r = 0; r < 4; ++r)
        dvals[mt][r] = deg[R0 + w * 32 + mt * 16 + quad * 4 + r];
  }

  __syncthreads();

  // GEMM1
  floatx4 zero4 = {0.f, 0.f, 0.f, 0.f};
  floatx4 acc[2][8];
#pragma unroll
  for (int mt = 0; mt < 2; ++mt)
#pragma unroll
    for (int t = 0; t < 8; ++t) acc[mt][t] = zero4;
#pragma unroll
  for (int s = 0; s < NS; ++s) {
    short8 bfrag[8];
#pragma unroll
    for (int t = 0; t < 8; ++t)
      bfrag[t] = *(const short8*)(lds + (s * 8 + t) * 1024 + lane * 16);
#pragma unroll
    for (int mt = 0; mt < 2; ++mt)
#pragma unroll
      for (int t = 0; t < 8; ++t)
        acc[mt][t] = __builtin_amdgcn_mfma_f32_16x16x32_bf16(afrag[s][mt], bfrag[t], acc[mt][t], 0, 0, 0);
  }

  __syncthreads();

  // stage W2T, write hidden A-slots
#pragma unroll
  for (int c = 0; c < 8; ++c) {
    int slot = w * 8 + c;
    int n = c * 16 + l16, k = w * 32 + quad * 8;
    gl_lds16(W2T + n * HH + k, lds + 32768 + slot * 1024 + lane * 16);
  }
  {
    floatx4 hv[2][8];
#pragma unroll
    for (int mt = 0; mt < 2; ++mt)
#pragma unroll
      for (int nt = 0; nt < 8; ++nt)
#pragma unroll
        for (int r = 0; r < 4; ++r) {
          float h = acc[mt][nt][r] + b1f[nt];
          if constexpr (MODE != 0) h += dvals[mt][r] * b2u[nt];
          hv[mt][nt][r] = h > 0.f ? h : 0.f;
        }
    write_aslots(lds, hv, w, quad, l16);
  }

  __syncthreads();

  // GEMM2 -> x_new
  floatx4 acc2[2][8];
#pragma unroll
  for (int mt = 0; mt < 2; ++mt)
#pragma unroll
    for (int t = 0; t < 8; ++t) acc2[mt][t] = zero4;
  gemm_lds<8>(lds, mtgb, acc2, lane);

  floatx4 xv[2][8];
#pragma unroll
  for (int mt = 0; mt < 2; ++mt)
#pragma unroll
    for (int nt = 0; nt < 8; ++nt)
#pragma unroll
      for (int r = 0; r < 4; ++r)
        xv[mt][nt][r] = acc2[mt][nt][r] + b2f[nt];

  if constexpr (MODE != 3) {
#pragma unroll
    for (int mt = 0; mt < 2; ++mt)
#pragma unroll
      for (int nt = 0; nt < 8; ++nt) {
        int col = nt * 16 + l16;
#pragma unroll
        for (int r = 0; r < 4; ++r) {
          int row = R0 + w * 32 + mt * 16 + quad * 4 + r;
          xout[(size_t)row * HH + col] = f2bf(xv[mt][nt][r]);
        }
      }
  }

  __syncthreads();  // GEMM2 LDS reads complete

  // x_new -> A-slots; stage phase-C W1 (msgW1a or headW1)
  write_aslots(lds, xv, w, quad, l16);
#pragma unroll
  for (int c = 0; c < 8; ++c) {
    int slot = w * 8 + c;
    int n = c * 16 + l16, k = w * 32 + quad * 8;
    gl_lds16(pqW1 + n * PQS + k, lds + 32768 + slot * 1024 + lane * 16);
  }

  __syncthreads();

  floatx4 accc[2][8];
#pragma unroll
  for (int mt = 0; mt < 2; ++mt)
#pragma unroll
    for (int t = 0; t < 8; ++t) accc[mt][t] = zero4;
  gemm_lds<8>(lds, mtgb, accc, lane);

  if constexpr (MODE == 3) {
    // head hidden = relu(accc + headB1)
    floatx4 h2[2][8];
#pragma unroll
    for (int mt = 0; mt < 2; ++mt)
#pragma unroll
      for (int nt = 0; nt < 8; ++nt)
#pragma unroll
        for (int r = 0; r < 4; ++r) {
          float h = accc[mt][nt][r] + pb1[nt];
          h2[mt][nt][r] = h > 0.f ? h : 0.f;
        }
    __syncthreads();  // done reading x A-slots
    write_aslots(lds, h2, w, quad, l16);
#pragma unroll
    for (int c = 0; c < 2; ++c) {
      int slot = w * 2 + c;
      int n = c * 16 + l16, k = w * 32 + quad * 8;
      gl_lds16(pq2W + n * 128 + k, lds + 32768 + slot * 1024 + lane * 16);
    }
    __syncthreads();
    floatx4 acco[2][2];
#pragma unroll
    for (int mt = 0; mt < 2; ++mt)
#pragma unroll
      for (int t = 0; t < 2; ++t) acco[mt][t] = zero4;
    gemm_lds<2>(lds, mtgb, acco, lane);
    float ob[2];
#pragma unroll
    for (int t = 0; t < 2; ++t) ob[t] = pq2B[t * 16 + l16];
#pragma unroll
    for (int mt = 0; mt < 2; ++mt)
#pragma unroll
      for (int nt = 0; nt < 2; ++nt) {
        int col = nt * 16 + l16;
#pragma unroll
        for (int r = 0; r < 4; ++r) {
          int row = R0 + w * 32 + mt * 16 + quad * 4 + r;
          out32[(size_t)row * 32 + col] = acco[mt][nt][r] + ob[nt];
        }
      }
  } else {
    // P = accc + msgB1 (fp32)
#pragma unroll
    for (int mt = 0; mt < 2; ++mt)
#pragma unroll
      for (int nt = 0; nt < 8; ++nt) {
        int col = nt * 16 + l16;
#pragma unroll
        for (int r = 0; r < 4; ++r) {
          int row = R0 + w * 32 + mt * 16 + quad * 4 + r;
          Pout[(size_t)row * HH + col] = accc[mt][nt][r] + pb1[nt];
        }
      }
    __syncthreads();  // W1a reads complete
#pragma unroll
    for (int c = 0; c < 8; ++c) {
      int slot = w * 8 + c;
      int n = c * 16 + l16, k = w * 32 + quad * 8;
      gl_lds16(pqW1 + n * 256 + 128 + k, lds + 32768 + slot * 1024 + lane * 16);
    }
    __syncthreads();
    floatx4 accq[2][8];
#pragma unroll
    for (int mt = 0; mt < 2; ++mt)
#pragma unroll
      for (int t = 0; t < 8; ++t) accq[mt][t] = zero4;
    gemm_lds<8>(lds, mtgb, accq, lane);
#pragma unroll
    for (int mt = 0; mt < 2; ++mt)
#pragma unroll
      for (int nt = 0; nt < 8; ++nt) {
        int col = nt * 16 + l16;
#pragma unroll
        for (int r = 0; r < 4; ++r) {
          int row = R0 + w * 32 + mt * 16 + quad * 4 + r;
          Qout[(size_t)row * HH + col] = f2bf(accq[mt][nt][r]);
        }
      }
  }
}

// ---------------- loss ----------------

__global__ void loss_kernel(const float* __restrict__ out32, const void* __restrict__ loc,
                            const void* __restrict__ yv, const int* __restrict__ dflag,
                            float* __restrict__ out, float* __restrict__ acc, int NB) {
  int fl = *dflag;
  int i = blockIdx.x * 256 + threadIdx.x;
  const float* o = out32 + (size_t)i * 32;
  float dsum = 0.f, fde = 0.f;
#pragma unroll
  for (int f = 0; f < 10; ++f) {
    float dx = o[f * 3 + 0] + rdf(loc, i * 30 + f * 3 + 0, fl) - rdf(yv, i * 30 + f * 3 + 0, fl);
    float dy = o[f * 3 + 1] + rdf(loc, i * 30 + f * 3 + 1, fl) - rdf(yv, i * 30 + f * 3 + 1, fl);
    float dz = o[f * 3 + 2] + rdf(loc, i * 30 + f * 3 + 2, fl) - rdf(yv, i * 30 + f * 3 + 2, fl);
    float d = sqrtf(dx * dx + dy * dy + dz * dz);
    dsum += d;
    if (f == 9) fde = d;
  }
#pragma unroll
  for (int m = 1; m < 16; m <<= 1) {
    dsum += __shfl_xor(dsum, m);
    fde += __shfl_xor(fde, m);
  }
  if ((threadIdx.x & 15) == 0) {
    int b = i >> 4;
    out[1 + b] = dsum / 160.0f;
    out[1 + NB + b] = fde / 16.0f;
    unsafeAtomicAdd(acc, dsum);
  }
}

__global__ void final_kernel(const float* __restrict__ acc, float* __restrict__ out, float inv) {
  if (threadIdx.x == 0) out[0] = *acc * inv;
}

// ---------------- host ----------------

extern "C" void kernel_launch(void* const* d_in, const int* in_sizes, int n_in,
                              void* d_out, int out_size, void* d_ws, size_t ws_size,
                              hipStream_t stream) {
  const void* loc = d_in[0];
  const void* vel = d_in[1];
  const void* yv = d_in[2];
  const int* eidx = (const int*)d_in[3];

  const int N = in_sizes[0] / 30;  // 32768
  const int E = in_sizes[3] / 2;   // 524288
  const int L = 7;
  const int NB = N / 16;

  const size_t MB = 1024 * 1024;
  char* ws = (char*)d_ws;
  short* x = (short*)ws;                     // N*128 bf16   [0,8)MB
  float* P = (float*)(ws + 8 * MB);          // N*128 f32    [8,24)MB
  short* Qs = (short*)(ws + 24 * MB);        // N*128 bf16   [24,32)MB
  short* Hagg = (short*)(ws + 32 * MB);      // N*128 bf16   [32,40)MB
  short* updW1Tf = (short*)(ws + 40 * MB);   // 7*128*256 bf16
  int* bsums = (int*)(ws + 41 * MB);         // <=128 ints
  short* wbase = (short*)(ws + 48 * MB);
  const unsigned long long OFF_EMBW1 = 0;
  const unsigned long long OFF_EMBW2 = 8192;
  const unsigned long long OFF_HEADW1 = 24576;
  const unsigned long long OFF_HEADW2 = 40960;
  const unsigned long long OFF_MSGW1 = 45056;
  const unsigned long long OFF_MSGW2 = 274432;
  const unsigned long long OFF_UPDW1 = 389120;
  const unsigned long long OFF_UPDW2 = 618496;
  short* embW1T = wbase + OFF_EMBW1;
  short* embW2T = wbase + OFF_EMBW2;
  short* headW1T = wbase + OFF_HEADW1;
  short* headW2T = wbase + OFF_HEADW2;
  short* msgW1T = wbase + OFF_MSGW1;
  short* msgW2T = wbase + OFF_MSGW2;
  short* updW1T = wbase + OFF_UPDW1;
  short* updW2T = wbase + OFF_UPDW2;
  float* bias = (float*)(ws + 49 * MB + 512 * 1024);
  float* embB1f = bias;
  float* embB2f = bias + 128;
  float* msgB1f = bias + 256;
  float* msgB2f = bias + 1152;
  float* updB1f = bias + 2048;
  float* updB2f = bias + 2944;
  float* headB1f = bias + 3840;
  float* headB2f = bias + 3968;
  float* b2U = bias + 4096;                            // 7*128 fp32
  int* counts = (int*)(ws + 49 * MB + 768 * 1024);     // N ints
  int* row_start = (int*)(ws + 50 * MB);               // N+1 ints
  int* cursor = (int*)(ws + 50 * MB + 256 * 1024);     // N ints
  float* deg = (float*)(ws + 50 * MB + 512 * 1024);    // N floats
  int* iflag = (int*)(ws + 50 * MB + 768 * 1024);
  int* dflag = iflag + 16;
  float* accp = (float*)(iflag + 32);
  int* ssrc = (int*)(ws + 51 * MB);                    // E ints [51,53)MB
  short* in64 = (short*)(ws + 53 * MB);                // N*64 bf16 [53,57)MB
  float* out32 = (float*)(ws + 57 * MB);               // N*32 f32  [57,61)MB

  const int NBLK = (N + 255) / 256;  // 128

  detect_zero<<<NBLK, 256, 0, stream>>>(eidx, iflag, dflag, counts, accp,
                                        (const uint32_t*)loc, N);
  hist_kernel<<<(E + 255) / 256, 256, 0, stream>>>(eidx, iflag, counts, E);
  scan_bsum<<<NBLK, 256, 0, stream>>>(counts, bsums, N);
  scan_final<<<NBLK, 256, 0, stream>>>(counts, bsums, row_start, cursor, deg, N, E);
  scatter_kernel<<<(E + 255) / 256, 256, 0, stream>>>(eidx, iflag, cursor, ssrc, E);

  pad_input<<<(N * 64) / 256, 256, 0, stream>>>(loc, vel, in64, dflag);

  {
    WPrep a;
    const void* srcs[8] = {d_in[5], d_in[7], d_in[17], d_in[19],
                           d_in[9], d_in[11], d_in[13], d_in[15]};
    unsigned long long offs[8] = {OFF_EMBW1, OFF_EMBW2, OFF_HEADW1, OFF_HEADW2,
                                  OFF_MSGW1, OFF_MSGW2, OFF_UPDW1, OFF_UPDW2};
    int Ls[8] = {1, 1, 1, 1, 7, 7, 7, 7};
    int Ks[8] = {60, 128, 128, 128, 256, 128, 256, 128};
    int Ns[8] = {128, 128, 128, 30, 128, 128, 128, 128};
    int Kps[8] = {64, 128, 128, 128, 256, 128, 256, 128};
    int Nps[8] = {128, 128, 128, 32, 128, 128, 128, 128};
    int cum = 0;
    for (int s = 0; s < 8; ++s) {
      a.src[s] = srcs[s]; a.dstoff[s] = offs[s];
      a.L[s] = Ls[s]; a.K[s] = Ks[s]; a.Nn[s] = Ns[s]; a.Kp[s] = Kps[s]; a.Np[s] = Nps[s];
      a.bstart[s] = cum;
      cum += (Ls[s] * Nps[s] * Kps[s] + 255) / 256;
    }
    a.bstart[8] = cum;
    prep_w<<<cum, 256, 0, stream>>>(a, wbase, dflag);
  }
  {
    BPrep a;
    const void* srcs[8] = {d_in[6], d_in[8], d_in[10], d_in[12],
                           d_in[14], d_in[16], d_in[18], d_in[20]};
    int ns[8] = {128, 128, 896, 896, 896, 896, 128, 30};
    int es[9] = {0, 128, 256, 1152, 2048, 2944, 3840, 3968, 4000};
    for (int s = 0; s < 8; ++s) { a.src[s] = srcs[s]; a.n[s] = ns[s]; a.estart[s] = es[s]; }
    a.estart[8] = es[8];
    prep_b<<<16, 256, 0, stream>>>(a, bias, dflag);
  }

  fold_kernel<<<900, 256, 0, stream>>>(updW1T, msgW2T, updW1Tf, msgB2f, b2U);

  // embed + P0/Q0
  mlp_fused<0><<<N / 128, 256, 0, stream>>>(in64, nullptr,
      embW1T, embB1f, embW2T, embB2f, nullptr, nullptr,
      msgW1T, msgB1f, nullptr, nullptr, x, P, Qs, nullptr);

  for (int l = 0; l < L; ++l) {
    edge_agg<<<(N + 3) / 4, 256, 0, stream>>>(P, (const uint32_t*)Qs, ssrc, row_start,
                                              (uint32_t*)Hagg, N);
    if (l < L - 1) {
      mlp_fused<2><<<N / 128, 256, 0, stream>>>(x, Hagg,
          updW1Tf + l * 128 * 256, updB1f + l * 128, updW2T + l * 128 * 128, updB2f + l * 128,
          deg, b2U + l * 128,
          msgW1T + (l + 1) * 128 * 256, msgB1f + (l + 1) * 128, nullptr, nullptr,
          x, P, Qs, nullptr);
    } else {
      mlp_fused<3><<<N / 128, 256, 0, stream>>>(x, Hagg,
          updW1Tf + l * 128 * 256, updB1f + l * 128, updW2T + l * 128 * 128, updB2f + l * 128,
          deg, b2U + l * 128,
          headW1T, headB1f, headW2T, headB2f,
          nullptr, nullptr, nullptr, out32);
    }
  }

  loss_kernel<<<N / 256, 256, 0, stream>>>(out32, loc, yv, dflag, (float*)d_out, accp, NB);
  final_kernel<<<1, 64, 0, stream>>>(accp, (float*)d_out, 1.0f / 327680.0f);
}

// Round 6
// 531.448 us; speedup vs baseline: 3.6740x; 1.0029x over previous
//
#include <hip/hip_runtime.h>
#include <hip/hip_bf16.h>
#include <stdint.h>

#define HH 128

typedef __attribute__((ext_vector_type(8))) short short8;
typedef __attribute__((ext_vector_type(4))) float floatx4;

typedef __attribute__((address_space(3))) uint32_t lds_u32_t;
typedef const __attribute__((address_space(1))) uint32_t gbl_u32_t;

__device__ __forceinline__ void gl_lds16(const void* g, void* l) {
  __builtin_amdgcn_global_load_lds((gbl_u32_t*)g, (lds_u32_t*)l, 16, 0, 0);
}

__device__ __forceinline__ float bf2f(short v) {
  union { uint32_t u; float f; } x; x.u = ((uint32_t)(uint16_t)v) << 16; return x.f;
}
__device__ __forceinline__ short f2bf(float f) {
  union { float f; uint32_t u; } x; x.f = f;
  uint32_t r = x.u + 0x7fffu + ((x.u >> 16) & 1u);
  return (short)(r >> 16);
}
__device__ __forceinline__ float rdf(const void* p, int i, int fl) {
  return fl ? bf2f(((const short*)p)[i]) : ((const float*)p)[i];
}

// ---------------- probe + zero kernel ----------------

__global__ void detect_zero(const int* __restrict__ eidx, int* iflag, int* dflag,
                            int* __restrict__ counts, float* accp,
                            const uint32_t* __restrict__ loc, int N) {
  int g = blockIdx.x * 256 + threadIdx.x;
  if (g < N) counts[g] = 0;
  if (blockIdx.x == 0) {
    __shared__ int nz, cnt;
    if (threadIdx.x == 0) { nz = 0; cnt = 0; *accp = 0.f; }
    __syncthreads();
    int any = 0;
    for (int i = threadIdx.x; i < 1024; i += 256) any |= (eidx[2 * i + 1] != 0);
    if (any) atomicOr(&nz, 1);
    uint32_t u = loc[threadIdx.x];
    int e = (u >> 7) & 0xFF;
    if (e >= 100 && e <= 140) atomicAdd(&cnt, 1);
    __syncthreads();
    if (threadIdx.x == 0) {
      *iflag = (nz == 0) ? 1 : 0;    // 1 => int64 layout
      *dflag = (cnt >= 192) ? 1 : 0; // 1 => bf16 tensors
    }
  }
}

// ---------------- prep kernels ----------------

__global__ void pad_input(const void* __restrict__ loc, const void* __restrict__ vel,
                          short* __restrict__ dst, const int* __restrict__ dflag) {
  int fl = *dflag;
  int idx = blockIdx.x * 256 + threadIdx.x;
  int j = idx & 63, i = idx >> 6;
  short v = 0;
  if (j < 60) {
    int f = j / 6, c = j % 6;
    float x = (c < 3) ? rdf(loc, (i * 10 + f) * 3 + c, fl)
                      : rdf(vel, (i * 10 + f) * 3 + (c - 3), fl);
    v = f2bf(x);
  }
  dst[idx] = v;
}

struct WPrep {
  const void* src[8];
  unsigned long long dstoff[8];
  int L[8], K[8], Nn[8], Kp[8], Np[8];
  int bstart[9];
};

__global__ void prep_w(WPrep a, short* __restrict__ wbase, const int* __restrict__ dflag) {
  int fl = *dflag;
  int b = blockIdx.x;
  int s = 0;
  while (b >= a.bstart[s + 1]) ++s;
  int idx = (b - a.bstart[s]) * 256 + threadIdx.x;
  int Kp = a.Kp[s], Np = a.Np[s], K = a.K[s], Nn = a.Nn[s];
  int tot = a.L[s] * Np * Kp;
  if (idx >= tot) return;
  int k = idx % Kp; int rest = idx / Kp; int n = rest % Np; int l = rest / Np;
  short v = 0;
  if (k < K && n < Nn) v = f2bf(rdf(a.src[s], (l * K + k) * Nn + n, fl));
  wbase[a.dstoff[s] + idx] = v;
}

struct BPrep {
  const void* src[8];
  int n[8];
  int estart[9];
};

__global__ void prep_b(BPrep a, float* __restrict__ bias, const int* __restrict__ dflag) {
  int fl = *dflag;
  int idx = blockIdx.x * 256 + threadIdx.x;
  if (idx >= a.estart[8]) return;
  int s = 0;
  while (idx >= a.estart[s + 1]) ++s;
  int j = idx - a.estart[s];
  bias[idx] = (j < a.n[s]) ? rdf(a.src[s], j, fl) : 0.0f;
}

// ---------------- W2-fold precompute ----------------

__global__ void fold_kernel(const short* __restrict__ updW1T, const short* __restrict__ msgW2T,
                            short* __restrict__ updW1Tf, const float* __restrict__ msgB2f,
                            float* __restrict__ b2U) {
  if (blockIdx.x < 896) {
    int idx = blockIdx.x * 256 + threadIdx.x;  // 7*128*256
    int k = idx & 255; int n = (idx >> 8) & 127; int l = idx >> 15;
    if (k < 128) { updW1Tf[idx] = updW1T[idx]; return; }
    int kk = k - 128;
    const short* w2 = msgW2T + l * 128 * 128;
    const short* u1 = updW1T + l * 128 * 256 + n * 256 + 128;
    float s = 0.f;
    for (int j = 0; j < 128; ++j) s += bf2f(w2[j * 128 + kk]) * bf2f(u1[j]);
    updW1Tf[idx] = f2bf(s);
  } else {
    int idx = (blockIdx.x - 896) * 256 + threadIdx.x;  // 7*128
    if (idx >= 7 * 128) return;
    int n = idx & 127, l = idx >> 7;
    const short* u1 = updW1T + l * 128 * 256 + n * 256 + 128;
    const float* b2 = msgB2f + l * 128;
    float s = 0.f;
    for (int j = 0; j < 128; ++j) s += b2[j] * bf2f(u1[j]);
    b2U[idx] = s;
  }
}

// ---------------- edge sort (counting sort by dst) ----------------

__global__ void hist_kernel(const int* __restrict__ eidx, const int* __restrict__ iflag,
                            int* __restrict__ counts, int E) {
  int e = blockIdx.x * 256 + threadIdx.x;
  if (e >= E) return;
  int fl = *iflag;
  int d = fl ? eidx[2 * (E + e)] : eidx[E + e];
  atomicAdd(&counts[d], 1);
}

__global__ void scan_bsum(const int* __restrict__ counts, int* __restrict__ bsums, int N) {
  int i = blockIdx.x * 256 + threadIdx.x;
  int v = (i < N) ? counts[i] : 0;
#pragma unroll
  for (int off = 1; off < 64; off <<= 1) v += __shfl_xor(v, off);
  __shared__ int ws4[4];
  if ((threadIdx.x & 63) == 0) ws4[threadIdx.x >> 6] = v;
  __syncthreads();
  if (threadIdx.x == 0) bsums[blockIdx.x] = ws4[0] + ws4[1] + ws4[2] + ws4[3];
}

__global__ void scan_final(const int* __restrict__ counts, const int* __restrict__ bsums,
                           int* __restrict__ row_start, int* __restrict__ cursor,
                           float* __restrict__ deg, int N, int E) {
  int t = threadIdx.x;
  __shared__ int shb[2];
  __shared__ int wsum[4];
  int v = (t < 128 && t < (int)blockIdx.x) ? bsums[t] : 0;
#pragma unroll
  for (int off = 1; off < 64; off <<= 1) v += __shfl_xor(v, off);
  if (t == 0) shb[0] = v;
  if (t == 64) shb[1] = v;
  int i = blockIdx.x * 256 + t;
  int c = (i < N) ? counts[i] : 0;
  int lane = t & 63, w = t >> 6;
  int x = c;
#pragma unroll
  for (int off = 1; off < 64; off <<= 1) {
    int u = __shfl_up(x, off);
    if (lane >= off) x += u;
  }
  if (lane == 63) wsum[w] = x;
  __syncthreads();
  int wpre = 0;
#pragma unroll
  for (int k = 0; k < 4; ++k)
    if (k < w) wpre += wsum[k];
  int excl = shb[0] + shb[1] + wpre + x - c;
  if (i < N) {
    row_start[i] = excl;
    cursor[i] = excl;
    deg[i] = (float)c;
  }
  if (i == N - 1) row_start[N] = E;
}

__global__ void scatter_kernel(const int* __restrict__ eidx, const int* __restrict__ iflag,
                               int* __restrict__ cursor, int* __restrict__ ssrc, int E) {
  int e = blockIdx.x * 256 + threadIdx.x;
  if (e >= E) return;
  int fl = *iflag;
  int d = fl ? eidx[2 * (E + e)] : eidx[E + e];
  int sv = fl ? eidx[2 * e] : eidx[e];
  int pos = atomicAdd(&cursor[d], 1);
  ssrc[pos] = sv;
}

// ---------------- edge aggregation: Hagg[d] = sum relu(P[d] + Q[src]) ----------------
// P and Q are both packed bf16x2 (u32 per lane-pair of columns)

__global__ __launch_bounds__(256)
void edge_agg(const uint32_t* __restrict__ Pp, const uint32_t* __restrict__ Qp,
              const int* __restrict__ ssrc, const int* __restrict__ row_start,
              uint32_t* __restrict__ Hagg, int Ntot) {
  int w = threadIdx.x >> 6, lane = threadIdx.x & 63;
  int d = blockIdx.x * 4 + w;
  if (d >= Ntot) return;
  uint32_t pv = Pp[(size_t)d * 64 + lane];
  float px = bf2f((short)(pv & 0xffff));
  float py = bf2f((short)(pv >> 16));
  int s0 = row_start[d], s1 = row_start[d + 1];
  float ax = 0.f, ay = 0.f;
  int e = s0;
  for (; e + 8 <= s1; e += 8) {
    int idx[8];
    uint32_t q[8];
#pragma unroll
    for (int u = 0; u < 8; ++u) idx[u] = ssrc[e + u];
#pragma unroll
    for (int u = 0; u < 8; ++u) q[u] = Qp[(size_t)idx[u] * 64 + lane];
#pragma unroll
    for (int u = 0; u < 8; ++u) {
      float hx = px + bf2f((short)(q[u] & 0xffff));
      float hy = py + bf2f((short)(q[u] >> 16));
      ax += hx > 0.f ? hx : 0.f;
      ay += hy > 0.f ? hy : 0.f;
    }
  }
  for (; e < s1; ++e) {
    int i0 = ssrc[e];
    uint32_t q0 = Qp[(size_t)i0 * 64 + lane];
    float hx = px + bf2f((short)(q0 & 0xffff));
    float hy = py + bf2f((short)(q0 >> 16));
    ax += hx > 0.f ? hx : 0.f;
    ay += hy > 0.f ? hy : 0.f;
  }
  uint32_t packed = (uint32_t)(uint16_t)f2bf(ax) | ((uint32_t)(uint16_t)f2bf(ay) << 16);
  Hagg[(size_t)d * 64 + lane] = packed;
}

// ---------------- fused MLP helpers (8-wave quadrant layout) ----------------
// Block: 512 threads = 8 waves, wave (wr = w>>1 in 0..3, wc = w&1 in 0..1)
// owns C quadrant rows [wr*32, wr*32+32), cols [wc*64, wc*64+64).
// A-slots (lds[0:32768)): slot (s2*8 + g), g = row-group 0..7 = wr*2+mt.
// B-slots (lds[32768:65536)): slot (s2*8 + t), t = col-tile 0..7.

// write wave's 32x64 C quadrant (v[mt][nt], nt<4) into A-slots
__device__ __forceinline__ void write_aslots_q(char* lds, const floatx4 v[2][4],
                                               int wr, int wc, int quad, int l16) {
#pragma unroll
  for (int mt = 0; mt < 2; ++mt) {
    int g = wr * 2 + mt;
#pragma unroll
    for (int nt = 0; nt < 4; ++nt) {
      int s2 = wc * 2 + (nt >> 1);
      int qc = (nt & 1) * 2 + (l16 >> 3);
      char* base = lds + (size_t)(s2 * 8 + g) * 1024 + 2 * (l16 & 7);
#pragma unroll
      for (int r = 0; r < 4; ++r)
        *(short*)(base + (quad * 4 + r + 16 * qc) * 16) = f2bf(v[mt][nt][r]);
    }
  }
}

// K=128 GEMM from LDS: A from A-slots (wave's row groups), B slot = s2*TS + wc*NT + nt
template <int NT, int TS>
__device__ __forceinline__ void gemm_q(const char* lds, int wr, int wc,
                                       floatx4 acc[2][NT], int lane) {
#pragma unroll
  for (int s2 = 0; s2 < 4; ++s2) {
    short8 af[2];
#pragma unroll
    for (int mt = 0; mt < 2; ++mt)
      af[mt] = *(const short8*)(lds + (s2 * 8 + wr * 2 + mt) * 1024 + lane * 16);
    short8 bf[NT];
#pragma unroll
    for (int nt = 0; nt < NT; ++nt)
      bf[nt] = *(const short8*)(lds + 32768 + (s2 * TS + wc * NT + nt) * 1024 + lane * 16);
#pragma unroll
    for (int mt = 0; mt < 2; ++mt)
#pragma unroll
      for (int nt = 0; nt < NT; ++nt)
        acc[mt][nt] = __builtin_amdgcn_mfma_f32_16x16x32_bf16(af[mt], bf[nt], acc[mt][nt], 0, 0, 0);
  }
}

// ---------------- fused MLP kernel ----------------
// MODE 0: embed (K1=64) -> x, then P/Q for layer 0
// MODE 2: upd (K1=256, W2-folded) -> x, then P/Q for next layer
// MODE 3: upd (layer 6) -> head MLP -> out32

template <int MODE>
__global__ __launch_bounds__(512, 2)
void mlp_fused(const short* __restrict__ Asrc, const short* __restrict__ Asrc2,
               const short* __restrict__ W1T, const float* __restrict__ b1,
               const short* __restrict__ W2T, const float* __restrict__ b2,
               const float* __restrict__ deg, const float* __restrict__ b2Uv,
               const short* __restrict__ pqW1, const float* __restrict__ pqB1,
               const short* __restrict__ pq2W, const float* __restrict__ pq2B,
               short* __restrict__ xout, short* __restrict__ Pout,
               short* __restrict__ Qout, float* __restrict__ out32) {
  constexpr int K1 = (MODE == 0) ? 64 : 256;
  constexpr int NS = K1 / 32;
  constexpr int PQS = (MODE == 3) ? 128 : 256;

  __shared__ __align__(16) char lds[65536];

  const int tid = threadIdx.x;
  const int w = tid >> 6, lane = tid & 63;
  const int quad = lane >> 4, l16 = lane & 15;
  const int wr = w >> 1, wc = w & 1;
  const int R0 = blockIdx.x * 128;
  const int CB = wc * 64;

  // stage W1T B-fragments: NS*8 slots, NS per wave
#pragma unroll
  for (int c = 0; c < NS; ++c) {
    int slot = w * NS + c;
    int s = slot >> 3, t = slot & 7;
    int n = t * 16 + l16, k = s * 32 + quad * 8;
    gl_lds16(W1T + n * K1 + k, lds + slot * 1024 + lane * 16);
  }

  // A fragments (rows wr*32 + mt*16 + l16)
  short8 afrag[NS][2];
  if constexpr (MODE == 0) {
#pragma unroll
    for (int mt = 0; mt < 2; ++mt) {
      int m = R0 + wr * 32 + mt * 16 + l16;
      const short* pr = Asrc + (size_t)m * 64;
#pragma unroll
      for (int s = 0; s < NS; ++s) afrag[s][mt] = *(const short8*)(pr + s * 32 + quad * 8);
    }
  } else {
#pragma unroll
    for (int mt = 0; mt < 2; ++mt) {
      int m = R0 + wr * 32 + mt * 16 + l16;
      const short* pr = Asrc + (size_t)m * HH;
      const short* ar = Asrc2 + (size_t)m * HH;
#pragma unroll
      for (int s = 0; s < 4; ++s) {
        afrag[s][mt] = *(const short8*)(pr + s * 32 + quad * 8);
        afrag[s + 4][mt] = *(const short8*)(ar + s * 32 + quad * 8);
      }
    }
  }

  float b1f[4], b2f[4], pb1[4], b2u[4];
  float dvals[2][4];
#pragma unroll
  for (int t = 0; t < 4; ++t) {
    int col = CB + t * 16 + l16;
    b1f[t] = b1[col];
    b2f[t] = b2[col];
    pb1[t] = pqB1[col];
  }
  if constexpr (MODE != 0) {
#pragma unroll
    for (int t = 0; t < 4; ++t) b2u[t] = b2Uv[CB + t * 16 + l16];
#pragma unroll
    for (int mt = 0; mt < 2; ++mt)
#pragma unroll
      for (int r = 0; r < 4; ++r)
        dvals[mt][r] = deg[R0 + wr * 32 + mt * 16 + quad * 4 + r];
  }

  __syncthreads();

  // GEMM1: hidden = A @ W1 (wave computes its 32x64 quadrant)
  floatx4 zero4 = {0.f, 0.f, 0.f, 0.f};
  floatx4 acc[2][4];
#pragma unroll
  for (int mt = 0; mt < 2; ++mt)
#pragma unroll
    for (int t = 0; t < 4; ++t) acc[mt][t] = zero4;
#pragma unroll
  for (int s = 0; s < NS; ++s) {
    short8 bfrag[4];
#pragma unroll
    for (int nt = 0; nt < 4; ++nt)
      bfrag[nt] = *(const short8*)(lds + (s * 8 + wc * 4 + nt) * 1024 + lane * 16);
#pragma unroll
    for (int mt = 0; mt < 2; ++mt)
#pragma unroll
      for (int nt = 0; nt < 4; ++nt)
        acc[mt][nt] = __builtin_amdgcn_mfma_f32_16x16x32_bf16(afrag[s][mt], bfrag[nt], acc[mt][nt], 0, 0, 0);
  }

  __syncthreads();

  // stage W2T (32 slots, 4 per wave); write hidden A-slots
#pragma unroll
  for (int c = 0; c < 4; ++c) {
    int slot = w * 4 + c;
    int s2 = slot >> 3, t = slot & 7;
    int n = t * 16 + l16, k = s2 * 32 + quad * 8;
    gl_lds16(W2T + n * HH + k, lds + 32768 + slot * 1024 + lane * 16);
  }
  {
    floatx4 hv[2][4];
#pragma unroll
    for (int mt = 0; mt < 2; ++mt)
#pragma unroll
      for (int nt = 0; nt < 4; ++nt)
#pragma unroll
        for (int r = 0; r < 4; ++r) {
          float h = acc[mt][nt][r] + b1f[nt];
          if constexpr (MODE != 0) h += dvals[mt][r] * b2u[nt];
          hv[mt][nt][r] = h > 0.f ? h : 0.f;
        }
    write_aslots_q(lds, hv, wr, wc, quad, l16);
  }

  __syncthreads();

  // GEMM2 -> x_new
  floatx4 acc2[2][4];
#pragma unroll
  for (int mt = 0; mt < 2; ++mt)
#pragma unroll
    for (int t = 0; t < 4; ++t) acc2[mt][t] = zero4;
  gemm_q<4, 8>(lds, wr, wc, acc2, lane);

  floatx4 xv[2][4];
#pragma unroll
  for (int mt = 0; mt < 2; ++mt)
#pragma unroll
    for (int nt = 0; nt < 4; ++nt)
#pragma unroll
      for (int r = 0; r < 4; ++r)
        xv[mt][nt][r] = acc2[mt][nt][r] + b2f[nt];

  if constexpr (MODE != 3) {
#pragma unroll
    for (int mt = 0; mt < 2; ++mt)
#pragma unroll
      for (int nt = 0; nt < 4; ++nt) {
        int col = CB + nt * 16 + l16;
#pragma unroll
        for (int r = 0; r < 4; ++r) {
          int row = R0 + wr * 32 + mt * 16 + quad * 4 + r;
          xout[(size_t)row * HH + col] = f2bf(xv[mt][nt][r]);
        }
      }
  }

  __syncthreads();  // all GEMM2 B reads complete

  // x_new -> A-slots; stage phase-C W1 (msgW1a or headW1)
  write_aslots_q(lds, xv, wr, wc, quad, l16);
#pragma unroll
  for (int c = 0; c < 4; ++c) {
    int slot = w * 4 + c;
    int s2 = slot >> 3, t = slot & 7;
    int n = t * 16 + l16, k = s2 * 32 + quad * 8;
    gl_lds16(pqW1 + n * PQS + k, lds + 32768 + slot * 1024 + lane * 16);
  }

  __syncthreads();

  floatx4 accc[2][4];
#pragma unroll
  for (int mt = 0; mt < 2; ++mt)
#pragma unroll
    for (int t = 0; t < 4; ++t) accc[mt][t] = zero4;
  gemm_q<4, 8>(lds, wr, wc, accc, lane);

  if constexpr (MODE == 3) {
    // head hidden = relu(accc + headB1)
    floatx4 h2[2][4];
#pragma unroll
    for (int mt = 0; mt < 2; ++mt)
#pragma unroll
      for (int nt = 0; nt < 4; ++nt)
#pragma unroll
        for (int r = 0; r < 4; ++r) {
          float h = accc[mt][nt][r] + pb1[nt];
          h2[mt][nt][r] = h > 0.f ? h : 0.f;
        }
    __syncthreads();  // all B reads (headW1) complete
    write_aslots_q(lds, h2, wr, wc, quad, l16);
    // stage headW2 (8 slots: s2*2+t, one per wave; w = s2*2+t)
    {
      int s2 = w >> 1, t = w & 1;
      int n = t * 16 + l16, k = s2 * 32 + quad * 8;
      gl_lds16(pq2W + n * 128 + k, lds + 32768 + w * 1024 + lane * 16);
    }
    __syncthreads();
    floatx4 acco[2][1];
#pragma unroll
    for (int mt = 0; mt < 2; ++mt) acco[mt][0] = zero4;
    gemm_q<1, 2>(lds, wr, wc, acco, lane);
    float ob = pq2B[wc * 16 + l16];
#pragma unroll
    for (int mt = 0; mt < 2; ++mt) {
      int col = wc * 16 + l16;
#pragma unroll
      for (int r = 0; r < 4; ++r) {
        int row = R0 + wr * 32 + mt * 16 + quad * 4 + r;
        out32[(size_t)row * 32 + col] = acco[mt][0][r] + ob;
      }
    }
  } else {
    // P (bf16) = accc + msgB1
#pragma unroll
    for (int mt = 0; mt < 2; ++mt)
#pragma unroll
      for (int nt = 0; nt < 4; ++nt) {
        int col = CB + nt * 16 + l16;
#pragma unroll
        for (int r = 0; r < 4; ++r) {
          int row = R0 + wr * 32 + mt * 16 + quad * 4 + r;
          Pout[(size_t)row * HH + col] = f2bf(accc[mt][nt][r] + pb1[nt]);
        }
      }
    __syncthreads();  // W1a B reads complete
#pragma unroll
    for (int c = 0; c < 4; ++c) {
      int slot = w * 4 + c;
      int s2 = slot >> 3, t = slot & 7;
      int n = t * 16 + l16, k = s2 * 32 + quad * 8;
      gl_lds16(pqW1 + n * 256 + 128 + k, lds + 32768 + slot * 1024 + lane * 16);
    }
    __syncthreads();
    floatx4 accq[2][4];
#pragma unroll
    for (int mt = 0; mt < 2; ++mt)
#pragma unroll
      for (int t = 0; t < 4; ++t) accq[mt][t] = zero4;
    gemm_q<4, 8>(lds, wr, wc, accq, lane);
#pragma unroll
    for (int mt = 0; mt < 2; ++mt)
#pragma unroll
      for (int nt = 0; nt < 4; ++nt) {
        int col = CB + nt * 16 + l16;
#pragma unroll
        for (int r = 0; r < 4; ++r) {
          int row = R0 + wr * 32 + mt * 16 + quad * 4 + r;
          Qout[(size_t)row * HH + col] = f2bf(accq[mt][nt][r]);
        }
      }
  }
}

// ---------------- loss ----------------

__global__ void loss_kernel(const float* __restrict__ out32, const void* __restrict__ loc,
                            const void* __restrict__ yv, const int* __restrict__ dflag,
                            float* __restrict__ out, float* __restrict__ acc, int NB) {
  int fl = *dflag;
  int i = blockIdx.x * 256 + threadIdx.x;
  const float* o = out32 + (size_t)i * 32;
  float dsum = 0.f, fde = 0.f;
#pragma unroll
  for (int f = 0; f < 10; ++f) {
    float dx = o[f * 3 + 0] + rdf(loc, i * 30 + f * 3 + 0, fl) - rdf(yv, i * 30 + f * 3 + 0, fl);
    float dy = o[f * 3 + 1] + rdf(loc, i * 30 + f * 3 + 1, fl) - rdf(yv, i * 30 + f * 3 + 1, fl);
    float dz = o[f * 3 + 2] + rdf(loc, i * 30 + f * 3 + 2, fl) - rdf(yv, i * 30 + f * 3 + 2, fl);
    float d = sqrtf(dx * dx + dy * dy + dz * dz);
    dsum += d;
    if (f == 9) fde = d;
  }
#pragma unroll
  for (int m = 1; m < 16; m <<= 1) {
    dsum += __shfl_xor(dsum, m);
    fde += __shfl_xor(fde, m);
  }
  if ((threadIdx.x & 15) == 0) {
    int b = i >> 4;
    out[1 + b] = dsum / 160.0f;
    out[1 + NB + b] = fde / 16.0f;
    unsafeAtomicAdd(acc, dsum);
  }
}

__global__ void final_kernel(const float* __restrict__ acc, float* __restrict__ out, float inv) {
  if (threadIdx.x == 0) out[0] = *acc * inv;
}

// ---------------- host ----------------

extern "C" void kernel_launch(void* const* d_in, const int* in_sizes, int n_in,
                              void* d_out, int out_size, void* d_ws, size_t ws_size,
                              hipStream_t stream) {
  const void* loc = d_in[0];
  const void* vel = d_in[1];
  const void* yv = d_in[2];
  const int* eidx = (const int*)d_in[3];

  const int N = in_sizes[0] / 30;  // 32768
  const int E = in_sizes[3] / 2;   // 524288
  const int L = 7;
  const int NB = N / 16;

  const size_t MB = 1024 * 1024;
  char* ws = (char*)d_ws;
  short* x = (short*)ws;                     // N*128 bf16   [0,8)MB
  short* P = (short*)(ws + 8 * MB);          // N*128 bf16   [8,16)MB
  short* Qs = (short*)(ws + 24 * MB);        // N*128 bf16   [24,32)MB
  short* Hagg = (short*)(ws + 32 * MB);      // N*128 bf16   [32,40)MB
  short* updW1Tf = (short*)(ws + 40 * MB);   // 7*128*256 bf16
  int* bsums = (int*)(ws + 41 * MB);         // <=128 ints
  short* wbase = (short*)(ws + 48 * MB);
  const unsigned long long OFF_EMBW1 = 0;
  const unsigned long long OFF_EMBW2 = 8192;
  const unsigned long long OFF_HEADW1 = 24576;
  const unsigned long long OFF_HEADW2 = 40960;
  const unsigned long long OFF_MSGW1 = 45056;
  const unsigned long long OFF_MSGW2 = 274432;
  const unsigned long long OFF_UPDW1 = 389120;
  const unsigned long long OFF_UPDW2 = 618496;
  short* embW1T = wbase + OFF_EMBW1;
  short* embW2T = wbase + OFF_EMBW2;
  short* headW1T = wbase + OFF_HEADW1;
  short* headW2T = wbase + OFF_HEADW2;
  short* msgW1T = wbase + OFF_MSGW1;
  short* msgW2T = wbase + OFF_MSGW2;
  short* updW1T = wbase + OFF_UPDW1;
  short* updW2T = wbase + OFF_UPDW2;
  float* bias = (float*)(ws + 49 * MB + 512 * 1024);
  float* embB1f = bias;
  float* embB2f = bias + 128;
  float* msgB1f = bias + 256;
  float* msgB2f = bias + 1152;
  float* updB1f = bias + 2048;
  float* updB2f = bias + 2944;
  float* headB1f = bias + 3840;
  float* headB2f = bias + 3968;
  float* b2U = bias + 4096;                            // 7*128 fp32
  int* counts = (int*)(ws + 49 * MB + 768 * 1024);     // N ints
  int* row_start = (int*)(ws + 50 * MB);               // N+1 ints
  int* cursor = (int*)(ws + 50 * MB + 256 * 1024);     // N ints
  float* deg = (float*)(ws + 50 * MB + 512 * 1024);    // N floats
  int* iflag = (int*)(ws + 50 * MB + 768 * 1024);
  int* dflag = iflag + 16;
  float* accp = (float*)(iflag + 32);
  int* ssrc = (int*)(ws + 51 * MB);                    // E ints [51,53)MB
  short* in64 = (short*)(ws + 53 * MB);                // N*64 bf16 [53,57)MB
  float* out32 = (float*)(ws + 57 * MB);               // N*32 f32  [57,61)MB

  const int NBLK = (N + 255) / 256;  // 128

  detect_zero<<<NBLK, 256, 0, stream>>>(eidx, iflag, dflag, counts, accp,
                                        (const uint32_t*)loc, N);
  hist_kernel<<<(E + 255) / 256, 256, 0, stream>>>(eidx, iflag, counts, E);
  scan_bsum<<<NBLK, 256, 0, stream>>>(counts, bsums, N);
  scan_final<<<NBLK, 256, 0, stream>>>(counts, bsums, row_start, cursor, deg, N, E);
  scatter_kernel<<<(E + 255) / 256, 256, 0, stream>>>(eidx, iflag, cursor, ssrc, E);

  pad_input<<<(N * 64) / 256, 256, 0, stream>>>(loc, vel, in64, dflag);

  {
    WPrep a;
    const void* srcs[8] = {d_in[5], d_in[7], d_in[17], d_in[19],
                           d_in[9], d_in[11], d_in[13], d_in[15]};
    unsigned long long offs[8] = {OFF_EMBW1, OFF_EMBW2, OFF_HEADW1, OFF_HEADW2,
                                  OFF_MSGW1, OFF_MSGW2, OFF_UPDW1, OFF_UPDW2};
    int Ls[8] = {1, 1, 1, 1, 7, 7, 7, 7};
    int Ks[8] = {60, 128, 128, 128, 256, 128, 256, 128};
    int Ns[8] = {128, 128, 128, 30, 128, 128, 128, 128};
    int Kps[8] = {64, 128, 128, 128, 256, 128, 256, 128};
    int Nps[8] = {128, 128, 128, 32, 128, 128, 128, 128};
    int cum = 0;
    for (int s = 0; s < 8; ++s) {
      a.src[s] = srcs[s]; a.dstoff[s] = offs[s];
      a.L[s] = Ls[s]; a.K[s] = Ks[s]; a.Nn[s] = Ns[s]; a.Kp[s] = Kps[s]; a.Np[s] = Nps[s];
      a.bstart[s] = cum;
      cum += (Ls[s] * Nps[s] * Kps[s] + 255) / 256;
    }
    a.bstart[8] = cum;
    prep_w<<<cum, 256, 0, stream>>>(a, wbase, dflag);
  }
  {
    BPrep a;
    const void* srcs[8] = {d_in[6], d_in[8], d_in[10], d_in[12],
                           d_in[14], d_in[16], d_in[18], d_in[20]};
    int ns[8] = {128, 128, 896, 896, 896, 896, 128, 30};
    int es[9] = {0, 128, 256, 1152, 2048, 2944, 3840, 3968, 4000};
    for (int s = 0; s < 8; ++s) { a.src[s] = srcs[s]; a.n[s] = ns[s]; a.estart[s] = es[s]; }
    a.estart[8] = es[8];
    prep_b<<<16, 256, 0, stream>>>(a, bias, dflag);
  }

  fold_kernel<<<900, 256, 0, stream>>>(updW1T, msgW2T, updW1Tf, msgB2f, b2U);

  // embed + P0/Q0
  mlp_fused<0><<<N / 128, 512, 0, stream>>>(in64, nullptr,
      embW1T, embB1f, embW2T, embB2f, nullptr, nullptr,
      msgW1T, msgB1f, nullptr, nullptr, x, P, Qs, nullptr);

  for (int l = 0; l < L; ++l) {
    edge_agg<<<(N + 3) / 4, 256, 0, stream>>>((const uint32_t*)P, (const uint32_t*)Qs,
                                              ssrc, row_start, (uint32_t*)Hagg, N);
    if (l < L - 1) {
      mlp_fused<2><<<N / 128, 512, 0, stream>>>(x, Hagg,
          updW1Tf + l * 128 * 256, updB1f + l * 128, updW2T + l * 128 * 128, updB2f + l * 128,
          deg, b2U + l * 128,
          msgW1T + (l + 1) * 128 * 256, msgB1f + (l + 1) * 128, nullptr, nullptr,
          x, P, Qs, nullptr);
    } else {
      mlp_fused<3><<<N / 128, 512, 0, stream>>>(x, Hagg,
          updW1Tf + l * 128 * 256, updB1f + l * 128, updW2T + l * 128 * 128, updB2f + l * 128,
          deg, b2U + l * 128,
          headW1T, headB1f, headW2T, headB2f,
          nullptr, nullptr, nullptr, out32);
    }
  }

  loss_kernel<<<N / 256, 256, 0, stream>>>(out32, loc, yv, dflag, (float*)d_out, accp, NB);
  final_kernel<<<1, 64, 0, stream>>>(accp, (float*)d_out, 1.0f / 327680.0f);
}